// Round 1
// 538.885 us; speedup vs baseline: 1.0733x; 1.0733x over previous
//
#include <hip/hip_runtime.h>
#include <hip/hip_bf16.h>

// Problem constants
#define D_   256
#define HW_  16384
#define B_   8
#define N_   256
#define S_   256
#define NH_  8
#define DH_  32
#define IMP_ 192
#define COV_ 64

// ---------------- workspace layout (byte offsets) ----------------
#define WS_SEL      ((size_t)0)                      // int32 [N][S]  (bit31 = scatter-suppress)
#define WS_KEYSB    ((size_t)262144)                 // bf16  [S][N][D]
#define WS_QK       ((size_t)33816576)               // f32   [N][8][256]
#define WS_QB       ((size_t)35913728)               // f32   [N][8]
#define WS_C1       ((size_t)35921920)               // f32   [N][256]
#define WS_WQT      ((size_t)36184064)               // f32   [256][256]  wqT[e][i]
#define WS_WVT      ((size_t)36446208)               // f32   [256][256]  wvT[d][i]
#define WS_WOUTT    ((size_t)36708352)               // f32   [256][256]  WoutT[j][i]
#define WS_SW1T     ((size_t)36970496)               // f32   [256][128]
#define WS_SW2T     ((size_t)37101568)               // f32   [128][128]
#define WS_W1AT     ((size_t)37167104)               // f32   [128][256]
#define WS_FW1B     ((size_t)37298176)               // bf16  [128][256]
#define WS_WFUSE    ((size_t)37363712)               // bf16  [256][128]  Wfuse[i][e] = seg_w1b . fw2
#define WS_ADDC     ((size_t)37429248)               // f32   [256]       addc[i] = seg_w1b . fb2

// attention partials live in d_out's out_seg region (zeroed AFTER attn_reduce)
#define PR_R_OFF  ((size_t)0)         // f32 [n][tile][h][256]  (4194304 floats)
#define PR_M_OFF  ((size_t)4194304)   // f32 [n][tile][h]
#define PR_L_OFF  ((size_t)4210688)   // f32 [n][tile][h]

typedef short bf16x8 __attribute__((ext_vector_type(8)));
typedef float f32x4  __attribute__((ext_vector_type(4)));

__device__ __forceinline__ unsigned short f2bf(float x){
  unsigned u = __float_as_uint(x);
  u = u + 0x7FFFu + ((u >> 16) & 1u);   // round-to-nearest-even
  return (unsigned short)(u >> 16);
}
__device__ __forceinline__ float bf2f(unsigned short h){
  return __uint_as_float(((unsigned)h) << 16);
}
// bijective LDS swizzle: toggles bank bits [5:1] with bits [10:6] -> pass-start
// reads (16 consecutive u16 per lane) become 2-way (free); scatter stays random.
__device__ __forceinline__ unsigned swz(unsigned p){ return p ^ (((p >> 6) & 31u) << 1); }

// ---------------- prep0: weight transposes / bf16 casts ----------------
__global__ __launch_bounds__(256) void prep0_kernel(
    const float* __restrict__ inW, const float* __restrict__ outW,
    const float* __restrict__ sw1, const float* __restrict__ sw2,
    const float* __restrict__ segw1, const float* __restrict__ fw1,
    char* __restrict__ ws)
{
  int idx = blockIdx.x * 256 + threadIdx.x;
  float* wqT   = (float*)(ws + WS_WQT);
  float* wvT   = (float*)(ws + WS_WVT);
  float* WoutT = (float*)(ws + WS_WOUTT);
  float* sw1T  = (float*)(ws + WS_SW1T);
  float* sw2T  = (float*)(ws + WS_SW2T);
  float* W1aT  = (float*)(ws + WS_W1AT);
  unsigned short* fw1b = (unsigned short*)(ws + WS_FW1B);
  if (idx < 65536){                       // wqT[e][i] = Wq[i][e]
    int e = idx >> 8, i = idx & 255; wqT[idx] = inW[i*256 + e];
  } else if (idx < 131072){               // wvT[d][i] = Wv[i][d]
    int r = idx - 65536; int d = r >> 8, i = r & 255; wvT[r] = inW[(512 + i)*256 + d];
  } else if (idx < 196608){               // WoutT[j][i] = Wout[i][j]
    int r = idx - 131072; int j = r >> 8, i = r & 255; WoutT[r] = outW[i*256 + j];
  } else if (idx < 229376){               // sw1T[e][t] = slot_w1[t][e]
    int r = idx - 196608; int e = r >> 7, t = r & 127; sw1T[r] = sw1[t*256 + e];
  } else if (idx < 245760){               // sw2T[e][j] = slot_w2[j][e]
    int r = idx - 229376; int e = r >> 7, j = r & 127; sw2T[r] = sw2[j*128 + e];
  } else if (idx < 278528){               // W1aT[j][i] = seg_w1[i][j], j<128
    int r = idx - 245760; int j = r >> 8, i = r & 255; W1aT[r] = segw1[i*256 + j];
  } else if (idx < 311296){               // fw1 bf16
    int r = idx - 278528; fw1b[r] = f2bf(fw1[r]);
  }
}

// ---------------- prep1: Wfuse = seg_w1[:,128:] @ fw2 ; addc = seg_w1[:,128:] @ fb2 ----------------
__global__ __launch_bounds__(128) void prep1_kernel(
    const float* __restrict__ segw1, const float* __restrict__ fw2,
    const float* __restrict__ fb2, char* __restrict__ ws)
{
  __shared__ float tmp[128];
  int i = blockIdx.x, t = threadIdx.x;   // t = e
  unsigned short* WfuseB = (unsigned short*)(ws + WS_WFUSE);
  float* addc = (float*)(ws + WS_ADDC);
  const float* w1b = segw1 + (size_t)i*256 + 128;
  float acc = 0.f;
  for (int k = 0; k < 128; k++) acc += w1b[k] * fw2[k*128 + t];
  WfuseB[i*128 + t] = f2bf(acc);
  tmp[t] = w1b[t] * fb2[t];
  __syncthreads();
  if (t == 0){
    float s = 0.f;
    for (int k = 0; k < 128; k++) s += tmp[k];
    addc[i] = s;
  }
}

// ---------------- qk: q = (slots@WqT+bq)/sqrt(DH); qk[n][h][e] = sum_dh q*Wk ----------------
__global__ __launch_bounds__(256) void qk_kernel(
    const float* __restrict__ slots, const float* __restrict__ inW,
    const float* __restrict__ inB, char* __restrict__ ws)
{
  __shared__ float sl[256];
  __shared__ float ql[256];
  int n = blockIdx.x, t = threadIdx.x;
  const float* wqT = (const float*)(ws + WS_WQT);
  float* qk = (float*)(ws + WS_QK);
  float* qb = (float*)(ws + WS_QB);
  sl[t] = slots[n*256 + t];
  __syncthreads();
  float acc = inB[t];
  for (int e = 0; e < 256; e++) acc += sl[e] * wqT[e*256 + t];
  ql[t] = acc * 0.17677669529663687f;   // 1/sqrt(32)
  __syncthreads();
  for (int h = 0; h < 8; h++){
    float a = 0.f;
    const float* wrow = inW + (size_t)(256 + h*32) * 256;
    #pragma unroll 4
    for (int dp = 0; dp < 32; dp++) a += ql[h*32 + dp] * wrow[dp*256 + t];
    qk[((size_t)n*8 + h)*256 + t] = a;
  }
  if (t < 8){
    float a = 0.f;
    for (int dp = 0; dp < 32; dp++) a += ql[t*32 + dp] * inB[256 + t*32 + dp];
    qb[n*8 + t] = a;
  }
}

// ---------------- sort: per-row stable LSD radix argsort (descending) + suppress bit ----------------
// v2: the 32-bit radix key is computed ONCE from a fully-coalesced float4 read and parked
// in a 64 KB LDS keybuf indexed by original element id (keys never move; only the index
// permutation moves). Each pass's digit fetch is a random ds_read_b32 (~6-12 cyc) instead
// of the previous per-pass random GLOBAL gather (~50-200 cyc L1/L2) -- that gather was
// ~1/3 of the kernel's 101 us.  Dynamic LDS 128 KB: keybuf u32[16384] | idxbuf u16[16384]
// (swizzled) | hist u16[16384].  Grid = 256 blocks = 1/CU, so 128 KB costs no occupancy.
__global__ __launch_bounds__(1024) void sort_kernel(
    const float* __restrict__ curio, const int* __restrict__ cov_sel,
    char* __restrict__ ws)
{
  extern __shared__ char smem_dyn[];
  unsigned*       keybuf = (unsigned*)smem_dyn;                   // 64 KB, by element id
  unsigned short* idxbuf = (unsigned short*)(smem_dyn + 65536);   // 32 KB (swizzled layout)
  unsigned short* hist   = (unsigned short*)(smem_dyn + 98304);   // 32 KB: slot = d*1024 + tid
  int n = blockIdx.x, tid = threadIdx.x;
  int lane = tid & 63, wid = tid >> 6;       // 16 waves
  const float* row = curio + (size_t)n * 16384;
  int* sel = (int*)(ws + WS_SEL);
  // one-time key transform, fully coalesced (4 x float4 per thread)
  {
    const float4* rowv = (const float4*)row;
    #pragma unroll
    for (int i = 0; i < 4; i++){
      float4 v = rowv[tid + i*1024];
      float vv[4] = {v.x, v.y, v.z, v.w};
      unsigned k4[4];
      #pragma unroll
      for (int c = 0; c < 4; c++){
        unsigned u = __float_as_uint(vv[c]);
        k4[c] = ((int)u < 0) ? u : (~u & 0x7fffffffu);  // ascending = value desc
      }
      uint4 w; w.x = k4[0]; w.y = k4[1]; w.z = k4[2]; w.w = k4[3];
      ((uint4*)keybuf)[tid + i*1024] = w;
    }
  }
  unsigned myidx[16]; unsigned myd[16];
  for (int pass = 0; pass < 8; pass++){
    unsigned* h32 = (unsigned*)hist;
    #pragma unroll
    for (int i = 0; i < 8; i++) h32[tid + i*1024] = 0;
    int base = tid * 16;
    if (pass == 0){
      #pragma unroll
      for (int i = 0; i < 16; i++) myidx[i] = base + i;
    } else {
      #pragma unroll
      for (int i = 0; i < 16; i++) myidx[i] = idxbuf[swz(base + i)];
    }
    __syncthreads();   // hist zeroed; keybuf (pass 0) / idxbuf reads complete
    int shift = pass * 4;
    #pragma unroll
    for (int i = 0; i < 16; i++){
      unsigned key = keybuf[myidx[i]];
      unsigned d = (key >> shift) & 15u;
      myd[i] = d;
      hist[d*1024 + tid]++;
    }
    __syncthreads();
    // exclusive scan over linear (digit-major, thread-minor) hist: 16384 entries, 16/thread
    unsigned v16[16]; unsigned srun = 0;
    #pragma unroll
    for (int j = 0; j < 16; j++) v16[j] = hist[tid*16 + j];
    #pragma unroll
    for (int j = 0; j < 16; j++){ unsigned tv = v16[j]; v16[j] = srun; srun += tv; }
    unsigned inc = srun;
    for (int dlt = 1; dlt < 64; dlt <<= 1){
      unsigned o = (unsigned)__shfl_up((int)inc, dlt, 64);
      if (lane >= dlt) inc += o;
    }
    unsigned* wtt = (unsigned*)idxbuf;   // scratch: idxbuf content is dead here (myidx in regs)
    if (lane == 63) wtt[wid] = inc;
    __syncthreads();
    if (tid == 0){ unsigned r = 0; for (int w = 0; w < 16; w++){ unsigned x = wtt[w]; wtt[w] = r; r += x; } }
    __syncthreads();
    unsigned off = wtt[wid] + (inc - srun);
    #pragma unroll
    for (int j = 0; j < 16; j++) hist[tid*16 + j] = (unsigned short)(v16[j] + off);
    __syncthreads();
    #pragma unroll
    for (int i = 0; i < 16; i++){
      unsigned d = myd[i];
      unsigned short pos = hist[d*1024 + tid];
      hist[d*1024 + tid] = (unsigned short)(pos + 1);
      idxbuf[swz(pos)] = (unsigned short)myidx[i];
    }
    __syncthreads();
  }
  // sel with suppress bit (numpy fancy-assign: largest s wins on duplicate j)
  int* sel_l = (int*)hist;   // hist dead after final scatter
  if (tid < 256){
    int s = tid;
    int rank = (s < IMP_) ? s : (IMP_ + cov_sel[s - IMP_]);
    sel_l[s] = (int)idxbuf[swz(rank)];
  }
  __syncthreads();
  if (tid < 256){
    int s = tid;
    int v = sel_l[s];
    if (s >= IMP_){
      for (int s2 = s + 1; s2 < 256; s2++)
        if (sel_l[s2] == v){ v |= 0x80000000; break; }
    }
    sel[n*256 + s] = v;
  }
}

// ---------------- attn_part: per (n, s-tile) gather + partial softmax stats; emits bf16 keys ----------------
__global__ __launch_bounds__(256) void attn_part_kernel(
    const float* __restrict__ features, const float* __restrict__ pos,
    const int* __restrict__ batch_idx, char* __restrict__ ws,
    float* __restrict__ part)
{
  __shared__ float qk_l[8*257];
  __shared__ float qb_l[8];
  __shared__ unsigned short keys_l[32*258];
  __shared__ unsigned short f_l[32*258];
  __shared__ float lg[32*9];
  int bx = blockIdx.x;
  int n = bx >> 3, tile = bx & 7;
  int t = threadIdx.x;
  const int* sel = (const int*)(ws + WS_SEL);
  unsigned short* keysb = (unsigned short*)(ws + WS_KEYSB);
  const float* qk  = (const float*)(ws + WS_QK);
  const float* qb  = (const float*)(ws + WS_QB);
  int b = batch_idx[n];
  #pragma unroll
  for (int r = 0; r < 8; r++){
    int idx = r*256 + t; int h = idx >> 8, d = idx & 255;
    qk_l[h*257 + d] = qk[((size_t)n*8 + h)*256 + d];
  }
  if (t < 8) qb_l[t] = qb[n*8 + t];
  int srow = t >> 3, chunk = t & 7;
  int s = tile*32 + srow;
  int hw = sel[n*256 + s] & 0x7fffffff;
  size_t gb = ((size_t)hw * 8 + (size_t)b) * 256 + (size_t)chunk*32;
  const float4* fp = (const float4*)(features + gb);
  const float4* pp = (const float4*)(pos + gb);
  float ff[32], kk[32];
  #pragma unroll
  for (int q = 0; q < 8; q++){
    float4 a = fp[q]; float4 c = pp[q];
    ff[q*4+0]=a.x; ff[q*4+1]=a.y; ff[q*4+2]=a.z; ff[q*4+3]=a.w;
    kk[q*4+0]=a.x+c.x; kk[q*4+1]=a.y+c.y; kk[q*4+2]=a.z+c.z; kk[q*4+3]=a.w+c.w;
  }
  unsigned kw[16], fw[16];
  #pragma unroll
  for (int p = 0; p < 16; p++){
    kw[p] = (unsigned)f2bf(kk[2*p]) | ((unsigned)f2bf(kk[2*p+1]) << 16);
    fw[p] = (unsigned)f2bf(ff[2*p]) | ((unsigned)f2bf(ff[2*p+1]) << 16);
  }
  unsigned* krow = (unsigned*)&keys_l[srow*258 + chunk*32];
  unsigned* frow = (unsigned*)&f_l[srow*258 + chunk*32];
  #pragma unroll
  for (int p = 0; p < 16; p++){ krow[p] = kw[p]; frow[p] = fw[p]; }
  uint4* gk = (uint4*)(keysb + ((size_t)s*256 + n)*256 + chunk*32);
  #pragma unroll
  for (int q = 0; q < 4; q++){
    uint4 u; u.x = kw[4*q]; u.y = kw[4*q+1]; u.z = kw[4*q+2]; u.w = kw[4*q+3];
    gk[q] = u;
  }
  __syncthreads();
  { // logits: thread = (s_local, h)
    int sl2 = t >> 3, h = t & 7;
    const unsigned* kp = (const unsigned*)&keys_l[sl2*258];
    const float* qh = &qk_l[h*257];
    float acc = qb_l[h];
    #pragma unroll 8
    for (int d2 = 0; d2 < 128; d2++){
      unsigned u = kp[d2];
      acc += bf2f((unsigned short)(u & 0xffffu)) * qh[2*d2]
           + bf2f((unsigned short)(u >> 16))     * qh[2*d2+1];
    }
    lg[sl2*9 + h] = acc;
  }
  __syncthreads();
  if (t < 8){ // per-tile softmax partial (no running state)
    float mt = -1e30f;
    for (int s2 = 0; s2 < 32; s2++) mt = fmaxf(mt, lg[s2*9 + t]);
    float ls = 0.f;
    for (int s2 = 0; s2 < 32; s2++){ float w = __expf(lg[s2*9 + t] - mt); lg[s2*9 + t] = w; ls += w; }
    part[PR_M_OFF + (size_t)(n*8 + tile)*8 + t] = mt;
    part[PR_L_OFF + (size_t)(n*8 + tile)*8 + t] = ls;
  }
  __syncthreads();
  { // r[h][d] partial (values = f)
    int h_r = t >> 5, dg = t & 31;
    float racc[8];
    #pragma unroll
    for (int j = 0; j < 8; j++) racc[j] = 0.f;
    for (int s2 = 0; s2 < 32; s2++){
      float w = lg[s2*9 + h_r];
      const unsigned short* fr = &f_l[s2*258];
      #pragma unroll
      for (int j = 0; j < 8; j++) racc[j] += w * bf2f(fr[dg + 32*j]);
    }
    float* pr = part + PR_R_OFF + ((size_t)(n*8 + tile)*8 + h_r)*256 + dg;
    #pragma unroll
    for (int j = 0; j < 8; j++) pr[32*j] = racc[j];
  }
}

// ---------------- attn_reduce: combine partials, Wv/Wout GEMVs, residual+LN -> out0; fused c1 ----------------
__global__ __launch_bounds__(256) void attn_reduce_kernel(
    const float* __restrict__ slots, const float* __restrict__ inB,
    const float* __restrict__ outB, const float* __restrict__ lng,
    const float* __restrict__ lnb, const float* __restrict__ sb1,
    const float* __restrict__ sb2, const float* __restrict__ segb1,
    char* __restrict__ ws, const float* __restrict__ part,
    float* __restrict__ out0)
{
  __shared__ float wt_l[8*8];  // [tile][h]
  __shared__ float r_l[8*257];
  __shared__ float o_l[256];
  __shared__ float red[4];
  __shared__ float so[256];
  __shared__ float h1[128];
  __shared__ float ps[128];
  int n = blockIdx.x, t = threadIdx.x;
  const float* wvT  = (const float*)(ws + WS_WVT);
  const float* WoT  = (const float*)(ws + WS_WOUTT);
  const float* sw1T = (const float*)(ws + WS_SW1T);
  const float* sw2T = (const float*)(ws + WS_SW2T);
  const float* W1aT = (const float*)(ws + WS_W1AT);
  const float* addc2 = (const float*)(ws + WS_ADDC);
  float* c1 = (float*)(ws + WS_C1);
  if (t < 8){
    float m8[8], l8[8];
    #pragma unroll
    for (int t8 = 0; t8 < 8; t8++){
      m8[t8] = part[PR_M_OFF + (size_t)(n*8 + t8)*8 + t];
      l8[t8] = part[PR_L_OFF + (size_t)(n*8 + t8)*8 + t];
    }
    float M = -1e30f;
    #pragma unroll
    for (int t8 = 0; t8 < 8; t8++) M = fmaxf(M, m8[t8]);
    float L = 0.f;
    #pragma unroll
    for (int t8 = 0; t8 < 8; t8++){
      float sc = __expf(m8[t8] - M);
      wt_l[t8*8 + t] = sc;
      L += l8[t8] * sc;
    }
    float inv = 1.f / L;
    #pragma unroll
    for (int t8 = 0; t8 < 8; t8++) wt_l[t8*8 + t] *= inv;
  }
  __syncthreads();
  {
    int h_r = t >> 5, dg = t & 31;
    float rj[8];
    #pragma unroll
    for (int j = 0; j < 8; j++) rj[j] = 0.f;
    for (int t8 = 0; t8 < 8; t8++){
      float w = wt_l[t8*8 + h_r];
      const float* pr = part + PR_R_OFF + ((size_t)(n*8 + t8)*8 + h_r)*256 + dg;
      #pragma unroll
      for (int j = 0; j < 8; j++) rj[j] += w * pr[32*j];
    }
    #pragma unroll
    for (int j = 0; j < 8; j++) r_l[h_r*257 + dg + 32*j] = rj[j];
  }
  __syncthreads();
  { // o[i] = sum_e r[h][e]*WvT[e][i] + bv[i]
    float acc = inB[512 + t];
    const float* rh = &r_l[(t >> 5)*257];
    for (int d = 0; d < 256; d++) acc += rh[d] * wvT[d*256 + t];
    o_l[t] = acc;
  }
  __syncthreads();
  float x;
  { // delta + residual
    float acc = outB[t];
    for (int j = 0; j < 256; j++) acc += o_l[j] * WoT[j*256 + t];
    x = slots[n*256 + t] + acc;
  }
  // layernorm over D
  int lane = t & 63, wid = t >> 6;
  float v = x;
  for (int o = 32; o > 0; o >>= 1) v += __shfl_xor(v, o, 64);
  if (lane == 0) red[wid] = v;
  __syncthreads();
  float mu = (red[0] + red[1] + red[2] + red[3]) * (1.f/256.f);
  float xc = x - mu;
  __syncthreads();
  float v2 = xc * xc;
  for (int o = 32; o > 0; o >>= 1) v2 += __shfl_xor(v2, o, 64);
  if (lane == 0) red[wid] = v2;
  __syncthreads();
  float var = (red[0] + red[1] + red[2] + red[3]) * (1.f/256.f);
  float xo = xc * rsqrtf(var + 1e-5f) * lng[t] + lnb[t];
  out0[n*256 + t] = xo;
  so[t] = xo;
  __syncthreads();
  // ---- fused c1: proj_slots MLP folded into seg layer-1 constant ----
  if (t < 128){
    float a = sb1[t];
    for (int e = 0; e < 256; e++) a += so[e] * sw1T[e*128 + t];
    h1[t] = fmaxf(a, 0.f);
  }
  __syncthreads();
  if (t < 128){
    float a = sb2[t];
    for (int e = 0; e < 128; e++) a += h1[e] * sw2T[e*128 + t];
    ps[t] = a;
  }
  __syncthreads();
  float a = segb1[t] + addc2[t];
  for (int j = 0; j < 128; j++) a += ps[j] * W1aT[j*256 + t];
  c1[n*256 + t] = a;
}

// ---------------- seg: fused MFMA chain keys->h1->(fused L2+seg L1)->3-way softmax + scatter ----------------
__global__ __launch_bounds__(256) void seg_kernel(
    const float* __restrict__ fb1, const float* __restrict__ segw2,
    const float* __restrict__ segb2, char* __restrict__ ws,
    float* __restrict__ out_seg, float* __restrict__ out_probs)
{
  __shared__ char smem[65024];
  unsigned short* A0   = (unsigned short*)smem;                       // [32][264]
  unsigned short* Bs   = (unsigned short*)(smem + 16896);             // [128][136]
  unsigned short* A1   = (unsigned short*)(smem + 16896 + 34816);     // [32][136]
  float* sw2_l = (float*)(smem + 16896 + 34816 + 8704);               // [3][256]
  float* lg3p  = (float*)(smem + 16896 + 34816 + 8704 + 3072);        // [4][32][3]
  int t = threadIdx.x;
  int wave = t >> 6, lane = t & 63, quad = lane >> 4, l15 = lane & 15;
  int rho0 = blockIdx.x * 32;
  int sg = rho0 >> 8, n0 = rho0 & 255;
  const unsigned short* keysb  = (const unsigned short*)(ws + WS_KEYSB);
  const unsigned short* fw1b   = (const unsigned short*)(ws + WS_FW1B);
  const unsigned short* WfuseB = (const unsigned short*)(ws + WS_WFUSE);
  const float* c1 = (const float*)(ws + WS_C1);
  const int* sel  = (const int*)(ws + WS_SEL);
  f32x4 zf = {0.f, 0.f, 0.f, 0.f};

  for (int i = t; i < 768; i += 256) sw2_l[i] = segw2[i];
  { // stage A0 = keys tile (32 rows x 256 bf16)
    int r = t >> 3, c8 = t & 7;
    const uint4* src = (const uint4*)(keysb + ((size_t)(rho0 + r))*256 + c8*32);
    uint4* dst = (uint4*)(A0 + r*264 + c8*32);
    #pragma unroll
    for (int q = 0; q < 4; q++) dst[q] = src[q];
  }
  // ---- GEMM1: [32x256]x[256->128] ----
  f32x4 acc[2][2];
  #pragma unroll
  for (int mt = 0; mt < 2; mt++)
    #pragma unroll
    for (int nt = 0; nt < 2; nt++) acc[mt][nt] = zf;
  for (int kh = 0; kh < 2; kh++){
    __syncthreads();
    { int r = t >> 1, h2 = t & 1;
      const uint4* src = (const uint4*)(fw1b + r*256 + kh*128 + h2*64);
      uint4* dst = (uint4*)(Bs + r*136 + h2*64);
      #pragma unroll
      for (int q = 0; q < 8; q++) dst[q] = src[q];
    }
    __syncthreads();
    #pragma unroll
    for (int ks = 0; ks < 4; ks++){
      int k = ks * 32;
      bf16x8 a[2], bb[2];
      #pragma unroll
      for (int mt = 0; mt < 2; mt++) a[mt]  = *(const bf16x8*)(A0 + (mt*16 + l15)*264 + kh*128 + k + quad*8);
      #pragma unroll
      for (int nt = 0; nt < 2; nt++) bb[nt] = *(const bf16x8*)(Bs + (wave*32 + nt*16 + l15)*136 + k + quad*8);
      #pragma unroll
      for (int mt = 0; mt < 2; mt++)
        #pragma unroll
        for (int nt = 0; nt < 2; nt++)
          acc[mt][nt] = __builtin_amdgcn_mfma_f32_16x16x32_bf16(a[mt], bb[nt], acc[mt][nt], 0, 0, 0);
    }
  }
  #pragma unroll
  for (int mt = 0; mt < 2; mt++)
    #pragma unroll
    for (int nt = 0; nt < 2; nt++){
      int col = wave*32 + nt*16 + l15;
      float bias = fb1[col];
      #pragma unroll
      for (int r = 0; r < 4; r++){
        int m = mt*16 + quad*4 + r;
        A1[m*136 + col] = f2bf(fmaxf(acc[mt][nt][r] + bias, 0.f));
      }
    }
  // ---- GEMMf: [32x128 (h1)] x [128->256 Wfuse], fused +c1, relu, x seg_w2 (N=3) ----
  float pl[2][4][3];
  #pragma unroll
  for (int mt = 0; mt < 2; mt++)
    #pragma unroll
    for (int r = 0; r < 4; r++)
      #pragma unroll
      for (int c = 0; c < 3; c++) pl[mt][r][c] = 0.f;
  for (int nh = 0; nh < 2; nh++){
    __syncthreads();
    { int r = t >> 1, h2 = t & 1;
      const uint4* src = (const uint4*)(WfuseB + (size_t)(nh*128 + r)*128 + h2*64);
      uint4* dst = (uint4*)(Bs + r*136 + h2*64);
      #pragma unroll
      for (int q = 0; q < 8; q++) dst[q] = src[q];
    }
    __syncthreads();
    f32x4 acc3[2][2];
    #pragma unroll
    for (int mt = 0; mt < 2; mt++)
      #pragma unroll
      for (int nt = 0; nt < 2; nt++) acc3[mt][nt] = zf;
    #pragma unroll
    for (int ks = 0; ks < 4; ks++){
      int k = ks * 32;
      bf16x8 a[2], bb[2];
      #pragma unroll
      for (int mt = 0; mt < 2; mt++) a[mt]  = *(const bf16x8*)(A1 + (mt*16 + l15)*136 + k + quad*8);
      #pragma unroll
      for (int nt = 0; nt < 2; nt++) bb[nt] = *(const bf16x8*)(Bs + (wave*32 + nt*16 + l15)*136 + k + quad*8);
      #pragma unroll
      for (int mt = 0; mt < 2; mt++)
        #pragma unroll
        for (int nt = 0; nt < 2; nt++)
          acc3[mt][nt] = __builtin_amdgcn_mfma_f32_16x16x32_bf16(a[mt], bb[nt], acc3[mt][nt], 0, 0, 0);
    }
    #pragma unroll
    for (int mt = 0; mt < 2; mt++)
      #pragma unroll
      for (int nt = 0; nt < 2; nt++){
        int i = nh*128 + wave*32 + nt*16 + l15;
        #pragma unroll
        for (int r = 0; r < 4; r++){
          int m = mt*16 + quad*4 + r;
          float hv = acc3[mt][nt][r] + c1[(size_t)(n0 + m)*256 + i];
          hv = fmaxf(hv, 0.f);
          #pragma unroll
          for (int c = 0; c < 3; c++) pl[mt][r][c] += hv * sw2_l[c*256 + i];
        }
      }
  }
  // reduce partial logits over the 16 lanes holding different i-columns
  #pragma unroll
  for (int off = 1; off < 16; off <<= 1){
    #pragma unroll
    for (int mt = 0; mt < 2; mt++)
      #pragma unroll
      for (int r = 0; r < 4; r++)
        #pragma unroll
        for (int c = 0; c < 3; c++)
          pl[mt][r][c] += __shfl_xor(pl[mt][r][c], off, 64);
  }
  if (l15 == 0){
    #pragma unroll
    for (int mt = 0; mt < 2; mt++)
      #pragma unroll
      for (int r = 0; r < 4; r++){
        int m = mt*16 + quad*4 + r;
        #pragma unroll
        for (int c = 0; c < 3; c++) lg3p[(wave*32 + m)*3 + c] = pl[mt][r][c];
      }
  }
  __syncthreads();
  if (t < 32){
    int m = t; int n = n0 + m;
    float L[3];
    #pragma unroll
    for (int c = 0; c < 3; c++)
      L[c] = segb2[c] + lg3p[(0*32 + m)*3 + c] + lg3p[(1*32 + m)*3 + c]
                      + lg3p[(2*32 + m)*3 + c] + lg3p[(3*32 + m)*3 + c];
    float mx = fmaxf(L[0], fmaxf(L[1], L[2]));
    float e0 = __expf(L[0] - mx), e1 = __expf(L[1] - mx), e2 = __expf(L[2] - mx);
    float inv = 1.f / (e0 + e1 + e2);
    float p0 = e0*inv, p1 = e1*inv, p2 = e2*inv;
    size_t rho = (size_t)rho0 + m;
    out_probs[rho*3 + 0] = p0; out_probs[rho*3 + 1] = p1; out_probs[rho*3 + 2] = p2;
    int v = sel[n*256 + sg];
    if (!(v & 0x80000000)){
      int j = v & 0x7fffffff;
      out_seg[((size_t)n*3 + 0)*16384 + j] = p0;
      out_seg[((size_t)n*3 + 1)*16384 + j] = p1;
      out_seg[((size_t)n*3 + 2)*16384 + j] = p2;
    }
  }
}

// ---------------- launch ----------------
extern "C" void kernel_launch(void* const* d_in, const int* in_sizes, int n_in,
                              void* d_out, int out_size, void* d_ws, size_t ws_size,
                              hipStream_t stream)
{
  (void)in_sizes; (void)n_in; (void)out_size; (void)ws_size;
  const float* features = (const float*)d_in[0];
  const float* pos      = (const float*)d_in[1];
  const int*   batch    = (const int*)d_in[2];
  const float* curio    = (const float*)d_in[3];
  const float* slots    = (const float*)d_in[5];
  const int*   cov_sel  = (const int*)d_in[6];
  const float* inW      = (const float*)d_in[7];
  const float* inB      = (const float*)d_in[8];
  const float* outW     = (const float*)d_in[9];
  const float* outB     = (const float*)d_in[10];
  const float* lng      = (const float*)d_in[11];
  const float* lnb      = (const float*)d_in[12];
  const float* sw1      = (const float*)d_in[13];
  const float* sb1      = (const float*)d_in[14];
  const float* sw2      = (const float*)d_in[15];
  const float* sb2      = (const float*)d_in[16];
  const float* fw1      = (const float*)d_in[17];
  const float* fb1      = (const float*)d_in[18];
  const float* fw2      = (const float*)d_in[19];
  const float* fb2      = (const float*)d_in[20];
  const float* segw1    = (const float*)d_in[21];
  const float* segb1    = (const float*)d_in[22];
  const float* segw2    = (const float*)d_in[23];
  const float* segb2    = (const float*)d_in[24];
  char* ws = (char*)d_ws;
  float* out0 = (float*)d_out;
  float* out_seg = out0 + 65536;                 // (N,3,HW)
  float* out_probs = out_seg + 12582912;         // (S,N,3)
  float* part = out_seg;                         // scratch overlay, zeroed before seg

  // allow 128 KB dynamic LDS for sort_kernel (gfx950 LDS/CU = 160 KB; grid = 1 block/CU)
  static bool s_attr_done = false;
  if (!s_attr_done){
    (void)hipFuncSetAttribute(reinterpret_cast<const void*>(sort_kernel),
                              hipFuncAttributeMaxDynamicSharedMemorySize, 131072);
    s_attr_done = true;
  }

  prep0_kernel<<<1216, 256, 0, stream>>>(inW, outW, sw1, sw2, segw1, fw1, ws);
  prep1_kernel<<<256, 128, 0, stream>>>(segw1, fw2, fb2, ws);
  qk_kernel<<<256, 256, 0, stream>>>(slots, inW, inB, ws);
  sort_kernel<<<256, 1024, 131072, stream>>>(curio, cov_sel, ws);
  attn_part_kernel<<<2048, 256, 0, stream>>>(features, pos, batch, ws, part);
  attn_reduce_kernel<<<256, 256, 0, stream>>>(slots, inB, outB, lng, lnb, sb1, sb2, segb1,
                                              ws, part, out0);
  hipMemsetAsync(out_seg, 0, (size_t)12582912 * 4, stream);
  seg_kernel<<<2048, 256, 0, stream>>>(fb1, segw2, segb2, ws, out_seg, out_probs);
}

// Round 2
// 535.440 us; speedup vs baseline: 1.0802x; 1.0064x over previous
//
#include <hip/hip_runtime.h>
#include <hip/hip_bf16.h>

// Problem constants
#define D_   256
#define HW_  16384
#define B_   8
#define N_   256
#define S_   256
#define NH_  8
#define DH_  32
#define IMP_ 192
#define COV_ 64

// ---------------- workspace layout (byte offsets) ----------------
#define WS_SEL      ((size_t)0)                      // int32 [N][S]  (bit31 = scatter-suppress)
#define WS_KEYSB    ((size_t)262144)                 // bf16  [S][N][D]
#define WS_QK       ((size_t)33816576)               // f32   [N][8][256]
#define WS_QB       ((size_t)35913728)               // f32   [N][8]
#define WS_C1       ((size_t)35921920)               // f32   [N][256]
#define WS_WQT      ((size_t)36184064)               // f32   [256][256]  wqT[e][i]
#define WS_WVT      ((size_t)36446208)               // f32   [256][256]  wvT[d][i]
#define WS_WOUTT    ((size_t)36708352)               // f32   [256][256]  WoutT[j][i]
#define WS_SW1T     ((size_t)36970496)               // f32   [256][128]
#define WS_SW2T     ((size_t)37101568)               // f32   [128][128]
#define WS_W1AT     ((size_t)37167104)               // f32   [128][256]
#define WS_FW1B     ((size_t)37298176)               // bf16  [128][256]
#define WS_WFUSE    ((size_t)37363712)               // bf16  [256][128]  Wfuse[i][e] = seg_w1b . fw2
#define WS_ADDC     ((size_t)37429248)               // f32   [256]       addc[i] = seg_w1b . fb2

// attention partials live in d_out's out_seg region (zeroed AFTER attn_reduce)
#define PR_R_OFF  ((size_t)0)         // f32 [n][tile][h][256]  (4194304 floats)
#define PR_M_OFF  ((size_t)4194304)   // f32 [n][tile][h]
#define PR_L_OFF  ((size_t)4210688)   // f32 [n][tile][h]

typedef short bf16x8 __attribute__((ext_vector_type(8)));
typedef float f32x4  __attribute__((ext_vector_type(4)));

__device__ __forceinline__ unsigned short f2bf(float x){
  unsigned u = __float_as_uint(x);
  u = u + 0x7FFFu + ((u >> 16) & 1u);   // round-to-nearest-even
  return (unsigned short)(u >> 16);
}
__device__ __forceinline__ float bf2f(unsigned short h){
  return __uint_as_float(((unsigned)h) << 16);
}
// bijective LDS swizzle: toggles bank bits [5:1] with bits [10:6] -> pass-start
// reads (16 consecutive u16 per lane) become 2-way (free); scatter stays random.
__device__ __forceinline__ unsigned swz(unsigned p){ return p ^ (((p >> 6) & 31u) << 1); }

// ---------------- prep0: weight transposes / bf16 casts ----------------
__global__ __launch_bounds__(256) void prep0_kernel(
    const float* __restrict__ inW, const float* __restrict__ outW,
    const float* __restrict__ sw1, const float* __restrict__ sw2,
    const float* __restrict__ segw1, const float* __restrict__ fw1,
    char* __restrict__ ws)
{
  int idx = blockIdx.x * 256 + threadIdx.x;
  float* wqT   = (float*)(ws + WS_WQT);
  float* wvT   = (float*)(ws + WS_WVT);
  float* WoutT = (float*)(ws + WS_WOUTT);
  float* sw1T  = (float*)(ws + WS_SW1T);
  float* sw2T  = (float*)(ws + WS_SW2T);
  float* W1aT  = (float*)(ws + WS_W1AT);
  unsigned short* fw1b = (unsigned short*)(ws + WS_FW1B);
  if (idx < 65536){                       // wqT[e][i] = Wq[i][e]
    int e = idx >> 8, i = idx & 255; wqT[idx] = inW[i*256 + e];
  } else if (idx < 131072){               // wvT[d][i] = Wv[i][d]
    int r = idx - 65536; int d = r >> 8, i = r & 255; wvT[r] = inW[(512 + i)*256 + d];
  } else if (idx < 196608){               // WoutT[j][i] = Wout[i][j]
    int r = idx - 131072; int j = r >> 8, i = r & 255; WoutT[r] = outW[i*256 + j];
  } else if (idx < 229376){               // sw1T[e][t] = slot_w1[t][e]
    int r = idx - 196608; int e = r >> 7, t = r & 127; sw1T[r] = sw1[t*256 + e];
  } else if (idx < 245760){               // sw2T[e][j] = slot_w2[j][e]
    int r = idx - 229376; int e = r >> 7, j = r & 127; sw2T[r] = sw2[j*128 + e];
  } else if (idx < 278528){               // W1aT[j][i] = seg_w1[i][j], j<128
    int r = idx - 245760; int j = r >> 8, i = r & 255; W1aT[r] = segw1[i*256 + j];
  } else if (idx < 311296){               // fw1 bf16
    int r = idx - 278528; fw1b[r] = f2bf(fw1[r]);
  }
}

// ---------------- prep1: Wfuse = seg_w1[:,128:] @ fw2 ; addc = seg_w1[:,128:] @ fb2 ----------------
__global__ __launch_bounds__(128) void prep1_kernel(
    const float* __restrict__ segw1, const float* __restrict__ fw2,
    const float* __restrict__ fb2, char* __restrict__ ws)
{
  __shared__ float tmp[128];
  int i = blockIdx.x, t = threadIdx.x;   // t = e
  unsigned short* WfuseB = (unsigned short*)(ws + WS_WFUSE);
  float* addc = (float*)(ws + WS_ADDC);
  const float* w1b = segw1 + (size_t)i*256 + 128;
  float acc = 0.f;
  for (int k = 0; k < 128; k++) acc += w1b[k] * fw2[k*128 + t];
  WfuseB[i*128 + t] = f2bf(acc);
  tmp[t] = w1b[t] * fb2[t];
  __syncthreads();
  if (t == 0){
    float s = 0.f;
    for (int k = 0; k < 128; k++) s += tmp[k];
    addc[i] = s;
  }
}

// ---------------- qk: q = (slots@WqT+bq)/sqrt(DH); qk[n][h][e] = sum_dh q*Wk ----------------
__global__ __launch_bounds__(256) void qk_kernel(
    const float* __restrict__ slots, const float* __restrict__ inW,
    const float* __restrict__ inB, char* __restrict__ ws)
{
  __shared__ float sl[256];
  __shared__ float ql[256];
  int n = blockIdx.x, t = threadIdx.x;
  const float* wqT = (const float*)(ws + WS_WQT);
  float* qk = (float*)(ws + WS_QK);
  float* qb = (float*)(ws + WS_QB);
  sl[t] = slots[n*256 + t];
  __syncthreads();
  float acc = inB[t];
  for (int e = 0; e < 256; e++) acc += sl[e] * wqT[e*256 + t];
  ql[t] = acc * 0.17677669529663687f;   // 1/sqrt(32)
  __syncthreads();
  for (int h = 0; h < 8; h++){
    float a = 0.f;
    const float* wrow = inW + (size_t)(256 + h*32) * 256;
    #pragma unroll 4
    for (int dp = 0; dp < 32; dp++) a += ql[h*32 + dp] * wrow[dp*256 + t];
    qk[((size_t)n*8 + h)*256 + t] = a;
  }
  if (t < 8){
    float a = 0.f;
    for (int dp = 0; dp < 32; dp++) a += ql[t*32 + dp] * inB[256 + t*32 + dp];
    qb[n*8 + t] = a;
  }
}

// ---------------- sort: per-row stable LSD radix argsort (descending) + suppress bit ----------------
// Keys computed once (coalesced) into a 64 KB LDS keybuf; all 8 passes' digit fetches are
// random ds_read_b32 instead of random global gathers. 128 KB dynamic LDS, 1 block/CU.
__global__ __launch_bounds__(1024) void sort_kernel(
    const float* __restrict__ curio, const int* __restrict__ cov_sel,
    char* __restrict__ ws)
{
  extern __shared__ char smem_dyn[];
  unsigned*       keybuf = (unsigned*)smem_dyn;                   // 64 KB, by element id
  unsigned short* idxbuf = (unsigned short*)(smem_dyn + 65536);   // 32 KB (swizzled layout)
  unsigned short* hist   = (unsigned short*)(smem_dyn + 98304);   // 32 KB: slot = d*1024 + tid
  int n = blockIdx.x, tid = threadIdx.x;
  int lane = tid & 63, wid = tid >> 6;       // 16 waves
  const float* row = curio + (size_t)n * 16384;
  int* sel = (int*)(ws + WS_SEL);
  // one-time key transform, fully coalesced (4 x float4 per thread)
  {
    const float4* rowv = (const float4*)row;
    #pragma unroll
    for (int i = 0; i < 4; i++){
      float4 v = rowv[tid + i*1024];
      float vv[4] = {v.x, v.y, v.z, v.w};
      unsigned k4[4];
      #pragma unroll
      for (int c = 0; c < 4; c++){
        unsigned u = __float_as_uint(vv[c]);
        k4[c] = ((int)u < 0) ? u : (~u & 0x7fffffffu);  // ascending = value desc
      }
      uint4 w; w.x = k4[0]; w.y = k4[1]; w.z = k4[2]; w.w = k4[3];
      ((uint4*)keybuf)[tid + i*1024] = w;
    }
  }
  unsigned myidx[16]; unsigned myd[16];
  for (int pass = 0; pass < 8; pass++){
    unsigned* h32 = (unsigned*)hist;
    #pragma unroll
    for (int i = 0; i < 8; i++) h32[tid + i*1024] = 0;
    int base = tid * 16;
    if (pass == 0){
      #pragma unroll
      for (int i = 0; i < 16; i++) myidx[i] = base + i;
    } else {
      #pragma unroll
      for (int i = 0; i < 16; i++) myidx[i] = idxbuf[swz(base + i)];
    }
    __syncthreads();   // hist zeroed; keybuf (pass 0) / idxbuf reads complete
    int shift = pass * 4;
    #pragma unroll
    for (int i = 0; i < 16; i++){
      unsigned key = keybuf[myidx[i]];
      unsigned d = (key >> shift) & 15u;
      myd[i] = d;
      hist[d*1024 + tid]++;
    }
    __syncthreads();
    // exclusive scan over linear (digit-major, thread-minor) hist: 16384 entries, 16/thread
    unsigned v16[16]; unsigned srun = 0;
    #pragma unroll
    for (int j = 0; j < 16; j++) v16[j] = hist[tid*16 + j];
    #pragma unroll
    for (int j = 0; j < 16; j++){ unsigned tv = v16[j]; v16[j] = srun; srun += tv; }
    unsigned inc = srun;
    for (int dlt = 1; dlt < 64; dlt <<= 1){
      unsigned o = (unsigned)__shfl_up((int)inc, dlt, 64);
      if (lane >= dlt) inc += o;
    }
    unsigned* wtt = (unsigned*)idxbuf;   // scratch: idxbuf content is dead here (myidx in regs)
    if (lane == 63) wtt[wid] = inc;
    __syncthreads();
    if (tid == 0){ unsigned r = 0; for (int w = 0; w < 16; w++){ unsigned x = wtt[w]; wtt[w] = r; r += x; } }
    __syncthreads();
    unsigned off = wtt[wid] + (inc - srun);
    #pragma unroll
    for (int j = 0; j < 16; j++) hist[tid*16 + j] = (unsigned short)(v16[j] + off);
    __syncthreads();
    #pragma unroll
    for (int i = 0; i < 16; i++){
      unsigned d = myd[i];
      unsigned short pos = hist[d*1024 + tid];
      hist[d*1024 + tid] = (unsigned short)(pos + 1);
      idxbuf[swz(pos)] = (unsigned short)myidx[i];
    }
    __syncthreads();
  }
  // sel with suppress bit (numpy fancy-assign: largest s wins on duplicate j)
  int* sel_l = (int*)hist;   // hist dead after final scatter
  if (tid < 256){
    int s = tid;
    int rank = (s < IMP_) ? s : (IMP_ + cov_sel[s - IMP_]);
    sel_l[s] = (int)idxbuf[swz(rank)];
  }
  __syncthreads();
  if (tid < 256){
    int s = tid;
    int v = sel_l[s];
    if (s >= IMP_){
      for (int s2 = s + 1; s2 < 256; s2++)
        if (sel_l[s2] == v){ v |= 0x80000000; break; }
    }
    sel[n*256 + s] = v;
  }
}

// ---------------- attn_part: per (n, s-tile) gather + partial softmax stats; emits bf16 keys ----------------
// v3: 16B-aligned LDS row strides (264 u16 / 260 f32) + explicit ds_read_b128 in the logits
// and r phases; r-phase remapped so each thread owns 8 consecutive d (1 b128/s-step instead
// of 8 ds_read_u16). Per-thread LDS instr count: logits 384->96, r-phase 288->64.
__global__ __launch_bounds__(256) void attn_part_kernel(
    const float* __restrict__ features, const float* __restrict__ pos,
    const int* __restrict__ batch_idx, char* __restrict__ ws,
    float* __restrict__ part)
{
  __shared__ __align__(16) float qk_l[8*260];
  __shared__ float qb_l[8];
  __shared__ __align__(16) unsigned short keys_l[32*264];
  __shared__ __align__(16) unsigned short f_l[32*264];
  __shared__ float lg[32*9];
  int bx = blockIdx.x;
  int n = bx >> 3, tile = bx & 7;
  int t = threadIdx.x;
  const int* sel = (const int*)(ws + WS_SEL);
  unsigned short* keysb = (unsigned short*)(ws + WS_KEYSB);
  const float* qk  = (const float*)(ws + WS_QK);
  const float* qb  = (const float*)(ws + WS_QB);
  int b = batch_idx[n];
  #pragma unroll
  for (int r = 0; r < 8; r++){
    int idx = r*256 + t; int h = idx >> 8, d = idx & 255;
    qk_l[h*260 + d] = qk[((size_t)n*8 + h)*256 + d];
  }
  if (t < 8) qb_l[t] = qb[n*8 + t];
  int srow = t >> 3, chunk = t & 7;
  int s = tile*32 + srow;
  int hw = sel[n*256 + s] & 0x7fffffff;
  size_t gb = ((size_t)hw * 8 + (size_t)b) * 256 + (size_t)chunk*32;
  const float4* fp = (const float4*)(features + gb);
  const float4* pp = (const float4*)(pos + gb);
  float ff[32], kk[32];
  #pragma unroll
  for (int q = 0; q < 8; q++){
    float4 a = fp[q]; float4 c = pp[q];
    ff[q*4+0]=a.x; ff[q*4+1]=a.y; ff[q*4+2]=a.z; ff[q*4+3]=a.w;
    kk[q*4+0]=a.x+c.x; kk[q*4+1]=a.y+c.y; kk[q*4+2]=a.z+c.z; kk[q*4+3]=a.w+c.w;
  }
  unsigned kw[16], fw[16];
  #pragma unroll
  for (int p = 0; p < 16; p++){
    kw[p] = (unsigned)f2bf(kk[2*p]) | ((unsigned)f2bf(kk[2*p+1]) << 16);
    fw[p] = (unsigned)f2bf(ff[2*p]) | ((unsigned)f2bf(ff[2*p+1]) << 16);
  }
  unsigned* krow = (unsigned*)&keys_l[srow*264 + chunk*32];
  unsigned* frow = (unsigned*)&f_l[srow*264 + chunk*32];
  #pragma unroll
  for (int p = 0; p < 16; p++){ krow[p] = kw[p]; frow[p] = fw[p]; }
  uint4* gk = (uint4*)(keysb + ((size_t)s*256 + n)*256 + chunk*32);
  #pragma unroll
  for (int q = 0; q < 4; q++){
    uint4 u; u.x = kw[4*q]; u.y = kw[4*q+1]; u.z = kw[4*q+2]; u.w = kw[4*q+3];
    gk[q] = u;
  }
  __syncthreads();
  { // logits: thread = (s_local, h); b128 reads of keys + q
    int sl2 = t >> 3, h = t & 7;
    const uint4*  kp4 = (const uint4*)&keys_l[sl2*264];
    const float4* qh4 = (const float4*)&qk_l[h*260];
    float acc = qb_l[h];
    #pragma unroll 4
    for (int d4 = 0; d4 < 32; d4++){
      uint4 u = kp4[d4];
      float4 qa = qh4[2*d4], qc = qh4[2*d4+1];
      acc += bf2f((unsigned short)(u.x & 0xffffu)) * qa.x
           + bf2f((unsigned short)(u.x >> 16))     * qa.y
           + bf2f((unsigned short)(u.y & 0xffffu)) * qa.z
           + bf2f((unsigned short)(u.y >> 16))     * qa.w
           + bf2f((unsigned short)(u.z & 0xffffu)) * qc.x
           + bf2f((unsigned short)(u.z >> 16))     * qc.y
           + bf2f((unsigned short)(u.w & 0xffffu)) * qc.z
           + bf2f((unsigned short)(u.w >> 16))     * qc.w;
    }
    lg[sl2*9 + h] = acc;
  }
  __syncthreads();
  if (t < 8){ // per-tile softmax partial (no running state)
    float mt = -1e30f;
    for (int s2 = 0; s2 < 32; s2++) mt = fmaxf(mt, lg[s2*9 + t]);
    float ls = 0.f;
    for (int s2 = 0; s2 < 32; s2++){ float w = __expf(lg[s2*9 + t] - mt); lg[s2*9 + t] = w; ls += w; }
    part[PR_M_OFF + (size_t)(n*8 + tile)*8 + t] = mt;
    part[PR_L_OFF + (size_t)(n*8 + tile)*8 + t] = ls;
  }
  __syncthreads();
  { // r[h][d] partial (values = f); thread owns d = dg*8 .. dg*8+7 (one b128 per s-step)
    int h_r = t >> 5, dg = t & 31;
    float racc[8];
    #pragma unroll
    for (int j = 0; j < 8; j++) racc[j] = 0.f;
    for (int s2 = 0; s2 < 32; s2++){
      float w = lg[s2*9 + h_r];
      uint4 u = *(const uint4*)&f_l[s2*264 + dg*8];
      racc[0] += w * bf2f((unsigned short)(u.x & 0xffffu));
      racc[1] += w * bf2f((unsigned short)(u.x >> 16));
      racc[2] += w * bf2f((unsigned short)(u.y & 0xffffu));
      racc[3] += w * bf2f((unsigned short)(u.y >> 16));
      racc[4] += w * bf2f((unsigned short)(u.z & 0xffffu));
      racc[5] += w * bf2f((unsigned short)(u.z >> 16));
      racc[6] += w * bf2f((unsigned short)(u.w & 0xffffu));
      racc[7] += w * bf2f((unsigned short)(u.w >> 16));
    }
    float* pr = part + PR_R_OFF + ((size_t)(n*8 + tile)*8 + h_r)*256 + dg*8;
    float4 o0 = {racc[0], racc[1], racc[2], racc[3]};
    float4 o1 = {racc[4], racc[5], racc[6], racc[7]};
    *(float4*)pr = o0;
    *(float4*)(pr + 4) = o1;
  }
}

// ---------------- attn_reduce: combine partials, Wv/Wout GEMVs, residual+LN -> out0; fused c1 ----------------
__global__ __launch_bounds__(256) void attn_reduce_kernel(
    const float* __restrict__ slots, const float* __restrict__ inB,
    const float* __restrict__ outB, const float* __restrict__ lng,
    const float* __restrict__ lnb, const float* __restrict__ sb1,
    const float* __restrict__ sb2, const float* __restrict__ segb1,
    char* __restrict__ ws, const float* __restrict__ part,
    float* __restrict__ out0)
{
  __shared__ float wt_l[8*8];  // [tile][h]
  __shared__ float r_l[8*257];
  __shared__ float o_l[256];
  __shared__ float red[4];
  __shared__ float so[256];
  __shared__ float h1[128];
  __shared__ float ps[128];
  int n = blockIdx.x, t = threadIdx.x;
  const float* wvT  = (const float*)(ws + WS_WVT);
  const float* WoT  = (const float*)(ws + WS_WOUTT);
  const float* sw1T = (const float*)(ws + WS_SW1T);
  const float* sw2T = (const float*)(ws + WS_SW2T);
  const float* W1aT = (const float*)(ws + WS_W1AT);
  const float* addc2 = (const float*)(ws + WS_ADDC);
  float* c1 = (float*)(ws + WS_C1);
  if (t < 8){
    float m8[8], l8[8];
    #pragma unroll
    for (int t8 = 0; t8 < 8; t8++){
      m8[t8] = part[PR_M_OFF + (size_t)(n*8 + t8)*8 + t];
      l8[t8] = part[PR_L_OFF + (size_t)(n*8 + t8)*8 + t];
    }
    float M = -1e30f;
    #pragma unroll
    for (int t8 = 0; t8 < 8; t8++) M = fmaxf(M, m8[t8]);
    float L = 0.f;
    #pragma unroll
    for (int t8 = 0; t8 < 8; t8++){
      float sc = __expf(m8[t8] - M);
      wt_l[t8*8 + t] = sc;
      L += l8[t8] * sc;
    }
    float inv = 1.f / L;
    #pragma unroll
    for (int t8 = 0; t8 < 8; t8++) wt_l[t8*8 + t] *= inv;
  }
  __syncthreads();
  { // combine partials; thread owns d = dg*8 .. dg*8+7 (matches attn_part layout)
    int h_r = t >> 5, dg = t & 31;
    float rj[8];
    #pragma unroll
    for (int j = 0; j < 8; j++) rj[j] = 0.f;
    for (int t8 = 0; t8 < 8; t8++){
      float w = wt_l[t8*8 + h_r];
      const float* pr = part + PR_R_OFF + ((size_t)(n*8 + t8)*8 + h_r)*256 + dg*8;
      float4 p0 = *(const float4*)pr;
      float4 p1 = *(const float4*)(pr + 4);
      rj[0] += w * p0.x; rj[1] += w * p0.y; rj[2] += w * p0.z; rj[3] += w * p0.w;
      rj[4] += w * p1.x; rj[5] += w * p1.y; rj[6] += w * p1.z; rj[7] += w * p1.w;
    }
    #pragma unroll
    for (int j = 0; j < 8; j++) r_l[h_r*257 + dg*8 + j] = rj[j];
  }
  __syncthreads();
  { // o[i] = sum_e r[h][e]*WvT[e][i] + bv[i]
    float acc = inB[512 + t];
    const float* rh = &r_l[(t >> 5)*257];
    for (int d = 0; d < 256; d++) acc += rh[d] * wvT[d*256 + t];
    o_l[t] = acc;
  }
  __syncthreads();
  float x;
  { // delta + residual
    float acc = outB[t];
    for (int j = 0; j < 256; j++) acc += o_l[j] * WoT[j*256 + t];
    x = slots[n*256 + t] + acc;
  }
  // layernorm over D
  int lane = t & 63, wid = t >> 6;
  float v = x;
  for (int o = 32; o > 0; o >>= 1) v += __shfl_xor(v, o, 64);
  if (lane == 0) red[wid] = v;
  __syncthreads();
  float mu = (red[0] + red[1] + red[2] + red[3]) * (1.f/256.f);
  float xc = x - mu;
  __syncthreads();
  float v2 = xc * xc;
  for (int o = 32; o > 0; o >>= 1) v2 += __shfl_xor(v2, o, 64);
  if (lane == 0) red[wid] = v2;
  __syncthreads();
  float var = (red[0] + red[1] + red[2] + red[3]) * (1.f/256.f);
  float xo = xc * rsqrtf(var + 1e-5f) * lng[t] + lnb[t];
  out0[n*256 + t] = xo;
  so[t] = xo;
  __syncthreads();
  // ---- fused c1: proj_slots MLP folded into seg layer-1 constant ----
  if (t < 128){
    float a = sb1[t];
    for (int e = 0; e < 256; e++) a += so[e] * sw1T[e*128 + t];
    h1[t] = fmaxf(a, 0.f);
  }
  __syncthreads();
  if (t < 128){
    float a = sb2[t];
    for (int e = 0; e < 128; e++) a += h1[e] * sw2T[e*128 + t];
    ps[t] = a;
  }
  __syncthreads();
  float a = segb1[t] + addc2[t];
  for (int j = 0; j < 128; j++) a += ps[j] * W1aT[j*256 + t];
  c1[n*256 + t] = a;
}

// ---------------- zero: exact 48 MiB streaming clear of out_seg (replaces runtime fill) ----------------
// 12582912 floats = 3145728 float4; 2048 blocks x 256 thr x 6 = 3145728 exactly.
__global__ __launch_bounds__(256) void zero_kernel(float4* __restrict__ p)
{
  int i = blockIdx.x * 256 + threadIdx.x;
  float4 z = {0.f, 0.f, 0.f, 0.f};
  #pragma unroll
  for (int q = 0; q < 6; q++) p[i + q*524288] = z;
}

// ---------------- seg: fused MFMA chain keys->h1->(fused L2+seg L1)->3-way softmax + scatter ----------------
__global__ __launch_bounds__(256) void seg_kernel(
    const float* __restrict__ fb1, const float* __restrict__ segw2,
    const float* __restrict__ segb2, char* __restrict__ ws,
    float* __restrict__ out_seg, float* __restrict__ out_probs)
{
  __shared__ char smem[65024];
  unsigned short* A0   = (unsigned short*)smem;                       // [32][264]
  unsigned short* Bs   = (unsigned short*)(smem + 16896);             // [128][136]
  unsigned short* A1   = (unsigned short*)(smem + 16896 + 34816);     // [32][136]
  float* sw2_l = (float*)(smem + 16896 + 34816 + 8704);               // [3][256]
  float* lg3p  = (float*)(smem + 16896 + 34816 + 8704 + 3072);        // [4][32][3]
  int t = threadIdx.x;
  int wave = t >> 6, lane = t & 63, quad = lane >> 4, l15 = lane & 15;
  int rho0 = blockIdx.x * 32;
  int sg = rho0 >> 8, n0 = rho0 & 255;
  const unsigned short* keysb  = (const unsigned short*)(ws + WS_KEYSB);
  const unsigned short* fw1b   = (const unsigned short*)(ws + WS_FW1B);
  const unsigned short* WfuseB = (const unsigned short*)(ws + WS_WFUSE);
  const float* c1 = (const float*)(ws + WS_C1);
  const int* sel  = (const int*)(ws + WS_SEL);
  f32x4 zf = {0.f, 0.f, 0.f, 0.f};

  for (int i = t; i < 768; i += 256) sw2_l[i] = segw2[i];
  { // stage A0 = keys tile (32 rows x 256 bf16)
    int r = t >> 3, c8 = t & 7;
    const uint4* src = (const uint4*)(keysb + ((size_t)(rho0 + r))*256 + c8*32);
    uint4* dst = (uint4*)(A0 + r*264 + c8*32);
    #pragma unroll
    for (int q = 0; q < 4; q++) dst[q] = src[q];
  }
  // ---- GEMM1: [32x256]x[256->128] ----
  f32x4 acc[2][2];
  #pragma unroll
  for (int mt = 0; mt < 2; mt++)
    #pragma unroll
    for (int nt = 0; nt < 2; nt++) acc[mt][nt] = zf;
  for (int kh = 0; kh < 2; kh++){
    __syncthreads();
    { int r = t >> 1, h2 = t & 1;
      const uint4* src = (const uint4*)(fw1b + r*256 + kh*128 + h2*64);
      uint4* dst = (uint4*)(Bs + r*136 + h2*64);
      #pragma unroll
      for (int q = 0; q < 8; q++) dst[q] = src[q];
    }
    __syncthreads();
    #pragma unroll
    for (int ks = 0; ks < 4; ks++){
      int k = ks * 32;
      bf16x8 a[2], bb[2];
      #pragma unroll
      for (int mt = 0; mt < 2; mt++) a[mt]  = *(const bf16x8*)(A0 + (mt*16 + l15)*264 + kh*128 + k + quad*8);
      #pragma unroll
      for (int nt = 0; nt < 2; nt++) bb[nt] = *(const bf16x8*)(Bs + (wave*32 + nt*16 + l15)*136 + k + quad*8);
      #pragma unroll
      for (int mt = 0; mt < 2; mt++)
        #pragma unroll
        for (int nt = 0; nt < 2; nt++)
          acc[mt][nt] = __builtin_amdgcn_mfma_f32_16x16x32_bf16(a[mt], bb[nt], acc[mt][nt], 0, 0, 0);
    }
  }
  #pragma unroll
  for (int mt = 0; mt < 2; mt++)
    #pragma unroll
    for (int nt = 0; nt < 2; nt++){
      int col = wave*32 + nt*16 + l15;
      float bias = fb1[col];
      #pragma unroll
      for (int r = 0; r < 4; r++){
        int m = mt*16 + quad*4 + r;
        A1[m*136 + col] = f2bf(fmaxf(acc[mt][nt][r] + bias, 0.f));
      }
    }
  // ---- GEMMf: [32x128 (h1)] x [128->256 Wfuse], fused +c1, relu, x seg_w2 (N=3) ----
  float pl[2][4][3];
  #pragma unroll
  for (int mt = 0; mt < 2; mt++)
    #pragma unroll
    for (int r = 0; r < 4; r++)
      #pragma unroll
      for (int c = 0; c < 3; c++) pl[mt][r][c] = 0.f;
  for (int nh = 0; nh < 2; nh++){
    __syncthreads();
    { int r = t >> 1, h2 = t & 1;
      const uint4* src = (const uint4*)(WfuseB + (size_t)(nh*128 + r)*128 + h2*64);
      uint4* dst = (uint4*)(Bs + r*136 + h2*64);
      #pragma unroll
      for (int q = 0; q < 8; q++) dst[q] = src[q];
    }
    __syncthreads();
    f32x4 acc3[2][2];
    #pragma unroll
    for (int mt = 0; mt < 2; mt++)
      #pragma unroll
      for (int nt = 0; nt < 2; nt++) acc3[mt][nt] = zf;
    #pragma unroll
    for (int ks = 0; ks < 4; ks++){
      int k = ks * 32;
      bf16x8 a[2], bb[2];
      #pragma unroll
      for (int mt = 0; mt < 2; mt++) a[mt]  = *(const bf16x8*)(A1 + (mt*16 + l15)*136 + k + quad*8);
      #pragma unroll
      for (int nt = 0; nt < 2; nt++) bb[nt] = *(const bf16x8*)(Bs + (wave*32 + nt*16 + l15)*136 + k + quad*8);
      #pragma unroll
      for (int mt = 0; mt < 2; mt++)
        #pragma unroll
        for (int nt = 0; nt < 2; nt++)
          acc3[mt][nt] = __builtin_amdgcn_mfma_f32_16x16x32_bf16(a[mt], bb[nt], acc3[mt][nt], 0, 0, 0);
    }
    #pragma unroll
    for (int mt = 0; mt < 2; mt++)
      #pragma unroll
      for (int nt = 0; nt < 2; nt++){
        int i = nh*128 + wave*32 + nt*16 + l15;
        #pragma unroll
        for (int r = 0; r < 4; r++){
          int m = mt*16 + quad*4 + r;
          float hv = acc3[mt][nt][r] + c1[(size_t)(n0 + m)*256 + i];
          hv = fmaxf(hv, 0.f);
          #pragma unroll
          for (int c = 0; c < 3; c++) pl[mt][r][c] += hv * sw2_l[c*256 + i];
        }
      }
  }
  // reduce partial logits over the 16 lanes holding different i-columns
  #pragma unroll
  for (int off = 1; off < 16; off <<= 1){
    #pragma unroll
    for (int mt = 0; mt < 2; mt++)
      #pragma unroll
      for (int r = 0; r < 4; r++)
        #pragma unroll
        for (int c = 0; c < 3; c++)
          pl[mt][r][c] += __shfl_xor(pl[mt][r][c], off, 64);
  }
  if (l15 == 0){
    #pragma unroll
    for (int mt = 0; mt < 2; mt++)
      #pragma unroll
      for (int r = 0; r < 4; r++){
        int m = mt*16 + quad*4 + r;
        #pragma unroll
        for (int c = 0; c < 3; c++) lg3p[(wave*32 + m)*3 + c] = pl[mt][r][c];
      }
  }
  __syncthreads();
  if (t < 32){
    int m = t; int n = n0 + m;
    float L[3];
    #pragma unroll
    for (int c = 0; c < 3; c++)
      L[c] = segb2[c] + lg3p[(0*32 + m)*3 + c] + lg3p[(1*32 + m)*3 + c]
                      + lg3p[(2*32 + m)*3 + c] + lg3p[(3*32 + m)*3 + c];
    float mx = fmaxf(L[0], fmaxf(L[1], L[2]));
    float e0 = __expf(L[0] - mx), e1 = __expf(L[1] - mx), e2 = __expf(L[2] - mx);
    float inv = 1.f / (e0 + e1 + e2);
    float p0 = e0*inv, p1 = e1*inv, p2 = e2*inv;
    size_t rho = (size_t)rho0 + m;
    out_probs[rho*3 + 0] = p0; out_probs[rho*3 + 1] = p1; out_probs[rho*3 + 2] = p2;
    int v = sel[n*256 + sg];
    if (!(v & 0x80000000)){
      int j = v & 0x7fffffff;
      out_seg[((size_t)n*3 + 0)*16384 + j] = p0;
      out_seg[((size_t)n*3 + 1)*16384 + j] = p1;
      out_seg[((size_t)n*3 + 2)*16384 + j] = p2;
    }
  }
}

// ---------------- launch ----------------
extern "C" void kernel_launch(void* const* d_in, const int* in_sizes, int n_in,
                              void* d_out, int out_size, void* d_ws, size_t ws_size,
                              hipStream_t stream)
{
  (void)in_sizes; (void)n_in; (void)out_size; (void)ws_size;
  const float* features = (const float*)d_in[0];
  const float* pos      = (const float*)d_in[1];
  const int*   batch    = (const int*)d_in[2];
  const float* curio    = (const float*)d_in[3];
  const float* slots    = (const float*)d_in[5];
  const int*   cov_sel  = (const int*)d_in[6];
  const float* inW      = (const float*)d_in[7];
  const float* inB      = (const float*)d_in[8];
  const float* outW     = (const float*)d_in[9];
  const float* outB     = (const float*)d_in[10];
  const float* lng      = (const float*)d_in[11];
  const float* lnb      = (const float*)d_in[12];
  const float* sw1      = (const float*)d_in[13];
  const float* sb1      = (const float*)d_in[14];
  const float* sw2      = (const float*)d_in[15];
  const float* sb2      = (const float*)d_in[16];
  const float* fw1      = (const float*)d_in[17];
  const float* fb1      = (const float*)d_in[18];
  const float* fw2      = (const float*)d_in[19];
  const float* fb2      = (const float*)d_in[20];
  const float* segw1    = (const float*)d_in[21];
  const float* segb1    = (const float*)d_in[22];
  const float* segw2    = (const float*)d_in[23];
  const float* segb2    = (const float*)d_in[24];
  char* ws = (char*)d_ws;
  float* out0 = (float*)d_out;
  float* out_seg = out0 + 65536;                 // (N,3,HW)
  float* out_probs = out_seg + 12582912;         // (S,N,3)
  float* part = out_seg;                         // scratch overlay, zeroed before seg

  // allow 128 KB dynamic LDS for sort_kernel (gfx950 LDS/CU = 160 KB; grid = 1 block/CU)
  static bool s_attr_done = false;
  if (!s_attr_done){
    (void)hipFuncSetAttribute(reinterpret_cast<const void*>(sort_kernel),
                              hipFuncAttributeMaxDynamicSharedMemorySize, 131072);
    s_attr_done = true;
  }

  prep0_kernel<<<1216, 256, 0, stream>>>(inW, outW, sw1, sw2, segw1, fw1, ws);
  prep1_kernel<<<256, 128, 0, stream>>>(segw1, fw2, fb2, ws);
  qk_kernel<<<256, 256, 0, stream>>>(slots, inW, inB, ws);
  sort_kernel<<<256, 1024, 131072, stream>>>(curio, cov_sel, ws);
  attn_part_kernel<<<2048, 256, 0, stream>>>(features, pos, batch, ws, part);
  attn_reduce_kernel<<<256, 256, 0, stream>>>(slots, inB, outB, lng, lnb, sb1, sb2, segb1,
                                              ws, part, out0);
  zero_kernel<<<2048, 256, 0, stream>>>((float4*)out_seg);
  seg_kernel<<<2048, 256, 0, stream>>>(fb1, segw2, segb2, ws, out_seg, out_probs);
}

// Round 3
// 517.278 us; speedup vs baseline: 1.1182x; 1.0351x over previous
//
#include <hip/hip_runtime.h>
#include <hip/hip_bf16.h>

// Problem constants
#define D_   256
#define HW_  16384
#define B_   8
#define N_   256
#define S_   256
#define NH_  8
#define DH_  32
#define IMP_ 192
#define COV_ 64

// ---------------- workspace layout (byte offsets) ----------------
#define WS_SEL      ((size_t)0)                      // int32 [N][S]  (bit31 = scatter-suppress)
#define WS_KEYSB    ((size_t)262144)                 // bf16  [S][N][D]
#define WS_QK       ((size_t)33816576)               // f32   [N][8][256]
#define WS_QB       ((size_t)35913728)               // f32   [N][8]
#define WS_C1       ((size_t)35921920)               // f32   [N][256]
#define WS_WQT      ((size_t)36184064)               // f32   [256][256]  wqT[e][i]
#define WS_WVT      ((size_t)36446208)               // f32   [256][256]  wvT[d][i]
#define WS_WOUTT    ((size_t)36708352)               // f32   [256][256]  WoutT[j][i]
#define WS_SW1T     ((size_t)36970496)               // f32   [256][128]
#define WS_SW2T     ((size_t)37101568)               // f32   [128][128]
#define WS_W1AT     ((size_t)37167104)               // f32   [128][256]
#define WS_FW1B     ((size_t)37298176)               // bf16  [128][256]
#define WS_WFUSE    ((size_t)37363712)               // bf16  [256][128]  Wfuse[i][e] = seg_w1b . fw2
#define WS_ADDC     ((size_t)37429248)               // f32   [256]       addc[i] = seg_w1b . fb2

// attention partials live in d_out's out_seg region (zeroed AFTER attn_reduce)
#define PR_R_OFF  ((size_t)0)         // f32 [n][tile][h][256]  (4194304 floats)
#define PR_M_OFF  ((size_t)4194304)   // f32 [n][tile][h]
#define PR_L_OFF  ((size_t)4210688)   // f32 [n][tile][h]

typedef short bf16x8 __attribute__((ext_vector_type(8)));
typedef float f32x4  __attribute__((ext_vector_type(4)));

__device__ __forceinline__ unsigned short f2bf(float x){
  unsigned u = __float_as_uint(x);
  u = u + 0x7FFFu + ((u >> 16) & 1u);   // round-to-nearest-even
  return (unsigned short)(u >> 16);
}
__device__ __forceinline__ float bf2f(unsigned short h){
  return __uint_as_float(((unsigned)h) << 16);
}
// bijective LDS swizzle: toggles bank bits [5:1] with bits [10:6] -> pass-start
// reads (16 consecutive u16 per lane) become 2-way (free); scatter stays random.
__device__ __forceinline__ unsigned swz(unsigned p){ return p ^ (((p >> 6) & 31u) << 1); }

// ---------------- prep0: weight transposes / bf16 casts ----------------
__global__ __launch_bounds__(256) void prep0_kernel(
    const float* __restrict__ inW, const float* __restrict__ outW,
    const float* __restrict__ sw1, const float* __restrict__ sw2,
    const float* __restrict__ segw1, const float* __restrict__ fw1,
    char* __restrict__ ws)
{
  int idx = blockIdx.x * 256 + threadIdx.x;
  float* wqT   = (float*)(ws + WS_WQT);
  float* wvT   = (float*)(ws + WS_WVT);
  float* WoutT = (float*)(ws + WS_WOUTT);
  float* sw1T  = (float*)(ws + WS_SW1T);
  float* sw2T  = (float*)(ws + WS_SW2T);
  float* W1aT  = (float*)(ws + WS_W1AT);
  unsigned short* fw1b = (unsigned short*)(ws + WS_FW1B);
  if (idx < 65536){                       // wqT[e][i] = Wq[i][e]
    int e = idx >> 8, i = idx & 255; wqT[idx] = inW[i*256 + e];
  } else if (idx < 131072){               // wvT[d][i] = Wv[i][d]
    int r = idx - 65536; int d = r >> 8, i = r & 255; wvT[r] = inW[(512 + i)*256 + d];
  } else if (idx < 196608){               // WoutT[j][i] = Wout[i][j]
    int r = idx - 131072; int j = r >> 8, i = r & 255; WoutT[r] = outW[i*256 + j];
  } else if (idx < 229376){               // sw1T[e][t] = slot_w1[t][e]
    int r = idx - 196608; int e = r >> 7, t = r & 127; sw1T[r] = sw1[t*256 + e];
  } else if (idx < 245760){               // sw2T[e][j] = slot_w2[j][e]
    int r = idx - 229376; int e = r >> 7, j = r & 127; sw2T[r] = sw2[j*128 + e];
  } else if (idx < 278528){               // W1aT[j][i] = seg_w1[i][j], j<128
    int r = idx - 245760; int j = r >> 8, i = r & 255; W1aT[r] = segw1[i*256 + j];
  } else if (idx < 311296){               // fw1 bf16
    int r = idx - 278528; fw1b[r] = f2bf(fw1[r]);
  }
}

// ---------------- prep1: Wfuse = seg_w1[:,128:] @ fw2 ; addc = seg_w1[:,128:] @ fb2 ----------------
__global__ __launch_bounds__(128) void prep1_kernel(
    const float* __restrict__ segw1, const float* __restrict__ fw2,
    const float* __restrict__ fb2, char* __restrict__ ws)
{
  __shared__ float tmp[128];
  int i = blockIdx.x, t = threadIdx.x;   // t = e
  unsigned short* WfuseB = (unsigned short*)(ws + WS_WFUSE);
  float* addc = (float*)(ws + WS_ADDC);
  const float* w1b = segw1 + (size_t)i*256 + 128;
  float acc = 0.f;
  #pragma unroll 16
  for (int k = 0; k < 128; k++) acc += w1b[k] * fw2[k*128 + t];
  WfuseB[i*128 + t] = f2bf(acc);
  tmp[t] = w1b[t] * fb2[t];
  __syncthreads();
  if (t == 0){
    float s = 0.f;
    #pragma unroll 16
    for (int k = 0; k < 128; k++) s += tmp[k];
    addc[i] = s;
  }
}

// ---------------- qk: q = (slots@WqT+bq)/sqrt(DH); qk[n][h][e] = sum_dh q*Wk ----------------
// unroll 16 on the GEMV loops: at 1 block/CU (1 wave/SIMD) there is no TLP to hide
// L2 latency; un-unrolled loops cost ~200 cyc/iteration. 16 loads in flight -> ~8x.
__global__ __launch_bounds__(256) void qk_kernel(
    const float* __restrict__ slots, const float* __restrict__ inW,
    const float* __restrict__ inB, char* __restrict__ ws)
{
  __shared__ float sl[256];
  __shared__ float ql[256];
  int n = blockIdx.x, t = threadIdx.x;
  const float* wqT = (const float*)(ws + WS_WQT);
  float* qk = (float*)(ws + WS_QK);
  float* qb = (float*)(ws + WS_QB);
  sl[t] = slots[n*256 + t];
  __syncthreads();
  float acc = inB[t];
  #pragma unroll 16
  for (int e = 0; e < 256; e++) acc += sl[e] * wqT[e*256 + t];
  ql[t] = acc * 0.17677669529663687f;   // 1/sqrt(32)
  __syncthreads();
  for (int h = 0; h < 8; h++){
    float a = 0.f;
    const float* wrow = inW + (size_t)(256 + h*32) * 256;
    #pragma unroll 16
    for (int dp = 0; dp < 32; dp++) a += ql[h*32 + dp] * wrow[dp*256 + t];
    qk[((size_t)n*8 + h)*256 + t] = a;
  }
  if (t < 8){
    float a = 0.f;
    #pragma unroll 8
    for (int dp = 0; dp < 32; dp++) a += ql[t*32 + dp] * inB[256 + t*32 + dp];
    qb[n*8 + t] = a;
  }
}

// ---------------- sort: per-row stable LSD radix argsort (descending) + suppress bit ----------------
// Keys computed once (coalesced) into a 64 KB LDS keybuf; all 8 passes' digit fetches are
// random ds_read_b32 instead of random global gathers. 128 KB dynamic LDS, 1 block/CU.
__global__ __launch_bounds__(1024) void sort_kernel(
    const float* __restrict__ curio, const int* __restrict__ cov_sel,
    char* __restrict__ ws)
{
  extern __shared__ char smem_dyn[];
  unsigned*       keybuf = (unsigned*)smem_dyn;                   // 64 KB, by element id
  unsigned short* idxbuf = (unsigned short*)(smem_dyn + 65536);   // 32 KB (swizzled layout)
  unsigned short* hist   = (unsigned short*)(smem_dyn + 98304);   // 32 KB: slot = d*1024 + tid
  int n = blockIdx.x, tid = threadIdx.x;
  int lane = tid & 63, wid = tid >> 6;       // 16 waves
  const float* row = curio + (size_t)n * 16384;
  int* sel = (int*)(ws + WS_SEL);
  // one-time key transform, fully coalesced (4 x float4 per thread)
  {
    const float4* rowv = (const float4*)row;
    #pragma unroll
    for (int i = 0; i < 4; i++){
      float4 v = rowv[tid + i*1024];
      float vv[4] = {v.x, v.y, v.z, v.w};
      unsigned k4[4];
      #pragma unroll
      for (int c = 0; c < 4; c++){
        unsigned u = __float_as_uint(vv[c]);
        k4[c] = ((int)u < 0) ? u : (~u & 0x7fffffffu);  // ascending = value desc
      }
      uint4 w; w.x = k4[0]; w.y = k4[1]; w.z = k4[2]; w.w = k4[3];
      ((uint4*)keybuf)[tid + i*1024] = w;
    }
  }
  unsigned myidx[16]; unsigned myd[16];
  for (int pass = 0; pass < 8; pass++){
    unsigned* h32 = (unsigned*)hist;
    #pragma unroll
    for (int i = 0; i < 8; i++) h32[tid + i*1024] = 0;
    int base = tid * 16;
    if (pass == 0){
      #pragma unroll
      for (int i = 0; i < 16; i++) myidx[i] = base + i;
    } else {
      #pragma unroll
      for (int i = 0; i < 16; i++) myidx[i] = idxbuf[swz(base + i)];
    }
    __syncthreads();   // hist zeroed; keybuf (pass 0) / idxbuf reads complete
    int shift = pass * 4;
    #pragma unroll
    for (int i = 0; i < 16; i++){
      unsigned key = keybuf[myidx[i]];
      unsigned d = (key >> shift) & 15u;
      myd[i] = d;
      hist[d*1024 + tid]++;
    }
    __syncthreads();
    // exclusive scan over linear (digit-major, thread-minor) hist: 16384 entries, 16/thread
    unsigned v16[16]; unsigned srun = 0;
    #pragma unroll
    for (int j = 0; j < 16; j++) v16[j] = hist[tid*16 + j];
    #pragma unroll
    for (int j = 0; j < 16; j++){ unsigned tv = v16[j]; v16[j] = srun; srun += tv; }
    unsigned inc = srun;
    for (int dlt = 1; dlt < 64; dlt <<= 1){
      unsigned o = (unsigned)__shfl_up((int)inc, dlt, 64);
      if (lane >= dlt) inc += o;
    }
    unsigned* wtt = (unsigned*)idxbuf;   // scratch: idxbuf content is dead here (myidx in regs)
    if (lane == 63) wtt[wid] = inc;
    __syncthreads();
    if (tid == 0){ unsigned r = 0; for (int w = 0; w < 16; w++){ unsigned x = wtt[w]; wtt[w] = r; r += x; } }
    __syncthreads();
    unsigned off = wtt[wid] + (inc - srun);
    #pragma unroll
    for (int j = 0; j < 16; j++) hist[tid*16 + j] = (unsigned short)(v16[j] + off);
    __syncthreads();
    #pragma unroll
    for (int i = 0; i < 16; i++){
      unsigned d = myd[i];
      unsigned short pos = hist[d*1024 + tid];
      hist[d*1024 + tid] = (unsigned short)(pos + 1);
      idxbuf[swz(pos)] = (unsigned short)myidx[i];
    }
    __syncthreads();
  }
  // sel with suppress bit (numpy fancy-assign: largest s wins on duplicate j)
  int* sel_l = (int*)hist;   // hist dead after final scatter
  if (tid < 256){
    int s = tid;
    int rank = (s < IMP_) ? s : (IMP_ + cov_sel[s - IMP_]);
    sel_l[s] = (int)idxbuf[swz(rank)];
  }
  __syncthreads();
  if (tid < 256){
    int s = tid;
    int v = sel_l[s];
    if (s >= IMP_){
      for (int s2 = s + 1; s2 < 256; s2++)
        if (sel_l[s2] == v){ v |= 0x80000000; break; }
    }
    sel[n*256 + s] = v;
  }
}

// ---------------- attn_part: per (n, s-tile) gather + partial softmax stats; emits bf16 keys ----------------
__global__ __launch_bounds__(256) void attn_part_kernel(
    const float* __restrict__ features, const float* __restrict__ pos,
    const int* __restrict__ batch_idx, char* __restrict__ ws,
    float* __restrict__ part)
{
  __shared__ __align__(16) float qk_l[8*260];
  __shared__ float qb_l[8];
  __shared__ __align__(16) unsigned short keys_l[32*264];
  __shared__ __align__(16) unsigned short f_l[32*264];
  __shared__ float lg[32*9];
  int bx = blockIdx.x;
  int n = bx >> 3, tile = bx & 7;
  int t = threadIdx.x;
  const int* sel = (const int*)(ws + WS_SEL);
  unsigned short* keysb = (unsigned short*)(ws + WS_KEYSB);
  const float* qk  = (const float*)(ws + WS_QK);
  const float* qb  = (const float*)(ws + WS_QB);
  int b = batch_idx[n];
  #pragma unroll
  for (int r = 0; r < 8; r++){
    int idx = r*256 + t; int h = idx >> 8, d = idx & 255;
    qk_l[h*260 + d] = qk[((size_t)n*8 + h)*256 + d];
  }
  if (t < 8) qb_l[t] = qb[n*8 + t];
  int srow = t >> 3, chunk = t & 7;
  int s = tile*32 + srow;
  int hw = sel[n*256 + s] & 0x7fffffff;
  size_t gb = ((size_t)hw * 8 + (size_t)b) * 256 + (size_t)chunk*32;
  const float4* fp = (const float4*)(features + gb);
  const float4* pp = (const float4*)(pos + gb);
  float ff[32], kk[32];
  #pragma unroll
  for (int q = 0; q < 8; q++){
    float4 a = fp[q]; float4 c = pp[q];
    ff[q*4+0]=a.x; ff[q*4+1]=a.y; ff[q*4+2]=a.z; ff[q*4+3]=a.w;
    kk[q*4+0]=a.x+c.x; kk[q*4+1]=a.y+c.y; kk[q*4+2]=a.z+c.z; kk[q*4+3]=a.w+c.w;
  }
  unsigned kw[16], fw[16];
  #pragma unroll
  for (int p = 0; p < 16; p++){
    kw[p] = (unsigned)f2bf(kk[2*p]) | ((unsigned)f2bf(kk[2*p+1]) << 16);
    fw[p] = (unsigned)f2bf(ff[2*p]) | ((unsigned)f2bf(ff[2*p+1]) << 16);
  }
  unsigned* krow = (unsigned*)&keys_l[srow*264 + chunk*32];
  unsigned* frow = (unsigned*)&f_l[srow*264 + chunk*32];
  #pragma unroll
  for (int p = 0; p < 16; p++){ krow[p] = kw[p]; frow[p] = fw[p]; }
  uint4* gk = (uint4*)(keysb + ((size_t)s*256 + n)*256 + chunk*32);
  #pragma unroll
  for (int q = 0; q < 4; q++){
    uint4 u; u.x = kw[4*q]; u.y = kw[4*q+1]; u.z = kw[4*q+2]; u.w = kw[4*q+3];
    gk[q] = u;
  }
  __syncthreads();
  { // logits: thread = (s_local, h); b128 reads of keys + q
    int sl2 = t >> 3, h = t & 7;
    const uint4*  kp4 = (const uint4*)&keys_l[sl2*264];
    const float4* qh4 = (const float4*)&qk_l[h*260];
    float acc = qb_l[h];
    #pragma unroll 4
    for (int d4 = 0; d4 < 32; d4++){
      uint4 u = kp4[d4];
      float4 qa = qh4[2*d4], qc = qh4[2*d4+1];
      acc += bf2f((unsigned short)(u.x & 0xffffu)) * qa.x
           + bf2f((unsigned short)(u.x >> 16))     * qa.y
           + bf2f((unsigned short)(u.y & 0xffffu)) * qa.z
           + bf2f((unsigned short)(u.y >> 16))     * qa.w
           + bf2f((unsigned short)(u.z & 0xffffu)) * qc.x
           + bf2f((unsigned short)(u.z >> 16))     * qc.y
           + bf2f((unsigned short)(u.w & 0xffffu)) * qc.z
           + bf2f((unsigned short)(u.w >> 16))     * qc.w;
    }
    lg[sl2*9 + h] = acc;
  }
  __syncthreads();
  if (t < 8){ // per-tile softmax partial (no running state)
    float mt = -1e30f;
    for (int s2 = 0; s2 < 32; s2++) mt = fmaxf(mt, lg[s2*9 + t]);
    float ls = 0.f;
    for (int s2 = 0; s2 < 32; s2++){ float w = __expf(lg[s2*9 + t] - mt); lg[s2*9 + t] = w; ls += w; }
    part[PR_M_OFF + (size_t)(n*8 + tile)*8 + t] = mt;
    part[PR_L_OFF + (size_t)(n*8 + tile)*8 + t] = ls;
  }
  __syncthreads();
  { // r[h][d] partial (values = f); thread owns d = dg*8 .. dg*8+7 (one b128 per s-step)
    int h_r = t >> 5, dg = t & 31;
    float racc[8];
    #pragma unroll
    for (int j = 0; j < 8; j++) racc[j] = 0.f;
    for (int s2 = 0; s2 < 32; s2++){
      float w = lg[s2*9 + h_r];
      uint4 u = *(const uint4*)&f_l[s2*264 + dg*8];
      racc[0] += w * bf2f((unsigned short)(u.x & 0xffffu));
      racc[1] += w * bf2f((unsigned short)(u.x >> 16));
      racc[2] += w * bf2f((unsigned short)(u.y & 0xffffu));
      racc[3] += w * bf2f((unsigned short)(u.y >> 16));
      racc[4] += w * bf2f((unsigned short)(u.z & 0xffffu));
      racc[5] += w * bf2f((unsigned short)(u.z >> 16));
      racc[6] += w * bf2f((unsigned short)(u.w & 0xffffu));
      racc[7] += w * bf2f((unsigned short)(u.w >> 16));
    }
    float* pr = part + PR_R_OFF + ((size_t)(n*8 + tile)*8 + h_r)*256 + dg*8;
    float4 o0 = {racc[0], racc[1], racc[2], racc[3]};
    float4 o1 = {racc[4], racc[5], racc[6], racc[7]};
    *(float4*)pr = o0;
    *(float4*)(pr + 4) = o1;
  }
}

// ---------------- attn_reduce: combine partials, Wv/Wout GEMVs, residual+LN -> out0; fused c1 ----------------
// unroll 16 on all GEMV loops (same latency argument as qk_kernel: 1 block/CU, no TLP).
__global__ __launch_bounds__(256) void attn_reduce_kernel(
    const float* __restrict__ slots, const float* __restrict__ inB,
    const float* __restrict__ outB, const float* __restrict__ lng,
    const float* __restrict__ lnb, const float* __restrict__ sb1,
    const float* __restrict__ sb2, const float* __restrict__ segb1,
    char* __restrict__ ws, const float* __restrict__ part,
    float* __restrict__ out0)
{
  __shared__ float wt_l[8*8];  // [tile][h]
  __shared__ float r_l[8*257];
  __shared__ float o_l[256];
  __shared__ float red[4];
  __shared__ float so[256];
  __shared__ float h1[128];
  __shared__ float ps[128];
  int n = blockIdx.x, t = threadIdx.x;
  const float* wvT  = (const float*)(ws + WS_WVT);
  const float* WoT  = (const float*)(ws + WS_WOUTT);
  const float* sw1T = (const float*)(ws + WS_SW1T);
  const float* sw2T = (const float*)(ws + WS_SW2T);
  const float* W1aT = (const float*)(ws + WS_W1AT);
  const float* addc2 = (const float*)(ws + WS_ADDC);
  float* c1 = (float*)(ws + WS_C1);
  if (t < 8){
    float m8[8], l8[8];
    #pragma unroll
    for (int t8 = 0; t8 < 8; t8++){
      m8[t8] = part[PR_M_OFF + (size_t)(n*8 + t8)*8 + t];
      l8[t8] = part[PR_L_OFF + (size_t)(n*8 + t8)*8 + t];
    }
    float M = -1e30f;
    #pragma unroll
    for (int t8 = 0; t8 < 8; t8++) M = fmaxf(M, m8[t8]);
    float L = 0.f;
    #pragma unroll
    for (int t8 = 0; t8 < 8; t8++){
      float sc = __expf(m8[t8] - M);
      wt_l[t8*8 + t] = sc;
      L += l8[t8] * sc;
    }
    float inv = 1.f / L;
    #pragma unroll
    for (int t8 = 0; t8 < 8; t8++) wt_l[t8*8 + t] *= inv;
  }
  __syncthreads();
  { // combine partials; thread owns d = dg*8 .. dg*8+7 (matches attn_part layout)
    int h_r = t >> 5, dg = t & 31;
    float rj[8];
    #pragma unroll
    for (int j = 0; j < 8; j++) rj[j] = 0.f;
    #pragma unroll
    for (int t8 = 0; t8 < 8; t8++){
      float w = wt_l[t8*8 + h_r];
      const float* pr = part + PR_R_OFF + ((size_t)(n*8 + t8)*8 + h_r)*256 + dg*8;
      float4 p0 = *(const float4*)pr;
      float4 p1 = *(const float4*)(pr + 4);
      rj[0] += w * p0.x; rj[1] += w * p0.y; rj[2] += w * p0.z; rj[3] += w * p0.w;
      rj[4] += w * p1.x; rj[5] += w * p1.y; rj[6] += w * p1.z; rj[7] += w * p1.w;
    }
    #pragma unroll
    for (int j = 0; j < 8; j++) r_l[h_r*257 + dg*8 + j] = rj[j];
  }
  __syncthreads();
  { // o[i] = sum_e r[h][e]*WvT[e][i] + bv[i]
    float acc = inB[512 + t];
    const float* rh = &r_l[(t >> 5)*257];
    #pragma unroll 16
    for (int d = 0; d < 256; d++) acc += rh[d] * wvT[d*256 + t];
    o_l[t] = acc;
  }
  __syncthreads();
  float x;
  { // delta + residual
    float acc = outB[t];
    #pragma unroll 16
    for (int j = 0; j < 256; j++) acc += o_l[j] * WoT[j*256 + t];
    x = slots[n*256 + t] + acc;
  }
  // layernorm over D
  int lane = t & 63, wid = t >> 6;
  float v = x;
  for (int o = 32; o > 0; o >>= 1) v += __shfl_xor(v, o, 64);
  if (lane == 0) red[wid] = v;
  __syncthreads();
  float mu = (red[0] + red[1] + red[2] + red[3]) * (1.f/256.f);
  float xc = x - mu;
  __syncthreads();
  float v2 = xc * xc;
  for (int o = 32; o > 0; o >>= 1) v2 += __shfl_xor(v2, o, 64);
  if (lane == 0) red[wid] = v2;
  __syncthreads();
  float var = (red[0] + red[1] + red[2] + red[3]) * (1.f/256.f);
  float xo = xc * rsqrtf(var + 1e-5f) * lng[t] + lnb[t];
  out0[n*256 + t] = xo;
  so[t] = xo;
  __syncthreads();
  // ---- fused c1: proj_slots MLP folded into seg layer-1 constant ----
  if (t < 128){
    float a = sb1[t];
    #pragma unroll 16
    for (int e = 0; e < 256; e++) a += so[e] * sw1T[e*128 + t];
    h1[t] = fmaxf(a, 0.f);
  }
  __syncthreads();
  if (t < 128){
    float a = sb2[t];
    #pragma unroll 16
    for (int e = 0; e < 128; e++) a += h1[e] * sw2T[e*128 + t];
    ps[t] = a;
  }
  __syncthreads();
  float a = segb1[t] + addc2[t];
  #pragma unroll 16
  for (int j = 0; j < 128; j++) a += ps[j] * W1aT[j*256 + t];
  c1[n*256 + t] = a;
}

// ---------------- zero: exact 48 MiB streaming clear of out_seg (replaces runtime fill) ----------------
// 12582912 floats = 3145728 float4; 2048 blocks x 256 thr x 6 = 3145728 exactly.
__global__ __launch_bounds__(256) void zero_kernel(float4* __restrict__ p)
{
  int i = blockIdx.x * 256 + threadIdx.x;
  float4 z = {0.f, 0.f, 0.f, 0.f};
  #pragma unroll
  for (int q = 0; q < 6; q++) p[i + q*524288] = z;
}

// ---------------- seg: fused MFMA chain keys->h1->(fused L2+seg L1)->3-way softmax + scatter ----------------
__global__ __launch_bounds__(256) void seg_kernel(
    const float* __restrict__ fb1, const float* __restrict__ segw2,
    const float* __restrict__ segb2, char* __restrict__ ws,
    float* __restrict__ out_seg, float* __restrict__ out_probs)
{
  __shared__ char smem[65024];
  unsigned short* A0   = (unsigned short*)smem;                       // [32][264]
  unsigned short* Bs   = (unsigned short*)(smem + 16896);             // [128][136]
  unsigned short* A1   = (unsigned short*)(smem + 16896 + 34816);     // [32][136]
  float* sw2_l = (float*)(smem + 16896 + 34816 + 8704);               // [3][256]
  float* lg3p  = (float*)(smem + 16896 + 34816 + 8704 + 3072);        // [4][32][3]
  int t = threadIdx.x;
  int wave = t >> 6, lane = t & 63, quad = lane >> 4, l15 = lane & 15;
  int rho0 = blockIdx.x * 32;
  int sg = rho0 >> 8, n0 = rho0 & 255;
  const unsigned short* keysb  = (const unsigned short*)(ws + WS_KEYSB);
  const unsigned short* fw1b   = (const unsigned short*)(ws + WS_FW1B);
  const unsigned short* WfuseB = (const unsigned short*)(ws + WS_WFUSE);
  const float* c1 = (const float*)(ws + WS_C1);
  const int* sel  = (const int*)(ws + WS_SEL);
  f32x4 zf = {0.f, 0.f, 0.f, 0.f};

  for (int i = t; i < 768; i += 256) sw2_l[i] = segw2[i];
  { // stage A0 = keys tile (32 rows x 256 bf16)
    int r = t >> 3, c8 = t & 7;
    const uint4* src = (const uint4*)(keysb + ((size_t)(rho0 + r))*256 + c8*32);
    uint4* dst = (uint4*)(A0 + r*264 + c8*32);
    #pragma unroll
    for (int q = 0; q < 4; q++) dst[q] = src[q];
  }
  // ---- GEMM1: [32x256]x[256->128] ----
  f32x4 acc[2][2];
  #pragma unroll
  for (int mt = 0; mt < 2; mt++)
    #pragma unroll
    for (int nt = 0; nt < 2; nt++) acc[mt][nt] = zf;
  for (int kh = 0; kh < 2; kh++){
    __syncthreads();
    { int r = t >> 1, h2 = t & 1;
      const uint4* src = (const uint4*)(fw1b + r*256 + kh*128 + h2*64);
      uint4* dst = (uint4*)(Bs + r*136 + h2*64);
      #pragma unroll
      for (int q = 0; q < 8; q++) dst[q] = src[q];
    }
    __syncthreads();
    #pragma unroll
    for (int ks = 0; ks < 4; ks++){
      int k = ks * 32;
      bf16x8 a[2], bb[2];
      #pragma unroll
      for (int mt = 0; mt < 2; mt++) a[mt]  = *(const bf16x8*)(A0 + (mt*16 + l15)*264 + kh*128 + k + quad*8);
      #pragma unroll
      for (int nt = 0; nt < 2; nt++) bb[nt] = *(const bf16x8*)(Bs + (wave*32 + nt*16 + l15)*136 + k + quad*8);
      #pragma unroll
      for (int mt = 0; mt < 2; mt++)
        #pragma unroll
        for (int nt = 0; nt < 2; nt++)
          acc[mt][nt] = __builtin_amdgcn_mfma_f32_16x16x32_bf16(a[mt], bb[nt], acc[mt][nt], 0, 0, 0);
    }
  }
  #pragma unroll
  for (int mt = 0; mt < 2; mt++)
    #pragma unroll
    for (int nt = 0; nt < 2; nt++){
      int col = wave*32 + nt*16 + l15;
      float bias = fb1[col];
      #pragma unroll
      for (int r = 0; r < 4; r++){
        int m = mt*16 + quad*4 + r;
        A1[m*136 + col] = f2bf(fmaxf(acc[mt][nt][r] + bias, 0.f));
      }
    }
  // ---- GEMMf: [32x128 (h1)] x [128->256 Wfuse], fused +c1, relu, x seg_w2 (N=3) ----
  float pl[2][4][3];
  #pragma unroll
  for (int mt = 0; mt < 2; mt++)
    #pragma unroll
    for (int r = 0; r < 4; r++)
      #pragma unroll
      for (int c = 0; c < 3; c++) pl[mt][r][c] = 0.f;
  for (int nh = 0; nh < 2; nh++){
    __syncthreads();
    { int r = t >> 1, h2 = t & 1;
      const uint4* src = (const uint4*)(WfuseB + (size_t)(nh*128 + r)*128 + h2*64);
      uint4* dst = (uint4*)(Bs + r*136 + h2*64);
      #pragma unroll
      for (int q = 0; q < 8; q++) dst[q] = src[q];
    }
    __syncthreads();
    f32x4 acc3[2][2];
    #pragma unroll
    for (int mt = 0; mt < 2; mt++)
      #pragma unroll
      for (int nt = 0; nt < 2; nt++) acc3[mt][nt] = zf;
    #pragma unroll
    for (int ks = 0; ks < 4; ks++){
      int k = ks * 32;
      bf16x8 a[2], bb[2];
      #pragma unroll
      for (int mt = 0; mt < 2; mt++) a[mt]  = *(const bf16x8*)(A1 + (mt*16 + l15)*136 + k + quad*8);
      #pragma unroll
      for (int nt = 0; nt < 2; nt++) bb[nt] = *(const bf16x8*)(Bs + (wave*32 + nt*16 + l15)*136 + k + quad*8);
      #pragma unroll
      for (int mt = 0; mt < 2; mt++)
        #pragma unroll
        for (int nt = 0; nt < 2; nt++)
          acc3[mt][nt] = __builtin_amdgcn_mfma_f32_16x16x32_bf16(a[mt], bb[nt], acc3[mt][nt], 0, 0, 0);
    }
    #pragma unroll
    for (int mt = 0; mt < 2; mt++)
      #pragma unroll
      for (int nt = 0; nt < 2; nt++){
        int i = nh*128 + wave*32 + nt*16 + l15;
        #pragma unroll
        for (int r = 0; r < 4; r++){
          int m = mt*16 + quad*4 + r;
          float hv = acc3[mt][nt][r] + c1[(size_t)(n0 + m)*256 + i];
          hv = fmaxf(hv, 0.f);
          #pragma unroll
          for (int c = 0; c < 3; c++) pl[mt][r][c] += hv * sw2_l[c*256 + i];
        }
      }
  }
  // reduce partial logits over the 16 lanes holding different i-columns
  #pragma unroll
  for (int off = 1; off < 16; off <<= 1){
    #pragma unroll
    for (int mt = 0; mt < 2; mt++)
      #pragma unroll
      for (int r = 0; r < 4; r++)
        #pragma unroll
        for (int c = 0; c < 3; c++)
          pl[mt][r][c] += __shfl_xor(pl[mt][r][c], off, 64);
  }
  if (l15 == 0){
    #pragma unroll
    for (int mt = 0; mt < 2; mt++)
      #pragma unroll
      for (int r = 0; r < 4; r++){
        int m = mt*16 + quad*4 + r;
        #pragma unroll
        for (int c = 0; c < 3; c++) lg3p[(wave*32 + m)*3 + c] = pl[mt][r][c];
      }
  }
  __syncthreads();
  if (t < 32){
    int m = t; int n = n0 + m;
    float L[3];
    #pragma unroll
    for (int c = 0; c < 3; c++)
      L[c] = segb2[c] + lg3p[(0*32 + m)*3 + c] + lg3p[(1*32 + m)*3 + c]
                      + lg3p[(2*32 + m)*3 + c] + lg3p[(3*32 + m)*3 + c];
    float mx = fmaxf(L[0], fmaxf(L[1], L[2]));
    float e0 = __expf(L[0] - mx), e1 = __expf(L[1] - mx), e2 = __expf(L[2] - mx);
    float inv = 1.f / (e0 + e1 + e2);
    float p0 = e0*inv, p1 = e1*inv, p2 = e2*inv;
    size_t rho = (size_t)rho0 + m;
    out_probs[rho*3 + 0] = p0; out_probs[rho*3 + 1] = p1; out_probs[rho*3 + 2] = p2;
    int v = sel[n*256 + sg];
    if (!(v & 0x80000000)){
      int j = v & 0x7fffffff;
      out_seg[((size_t)n*3 + 0)*16384 + j] = p0;
      out_seg[((size_t)n*3 + 1)*16384 + j] = p1;
      out_seg[((size_t)n*3 + 2)*16384 + j] = p2;
    }
  }
}

// ---------------- launch ----------------
extern "C" void kernel_launch(void* const* d_in, const int* in_sizes, int n_in,
                              void* d_out, int out_size, void* d_ws, size_t ws_size,
                              hipStream_t stream)
{
  (void)in_sizes; (void)n_in; (void)out_size; (void)ws_size;
  const float* features = (const float*)d_in[0];
  const float* pos      = (const float*)d_in[1];
  const int*   batch    = (const int*)d_in[2];
  const float* curio    = (const float*)d_in[3];
  const float* slots    = (const float*)d_in[5];
  const int*   cov_sel  = (const int*)d_in[6];
  const float* inW      = (const float*)d_in[7];
  const float* inB      = (const float*)d_in[8];
  const float* outW     = (const float*)d_in[9];
  const float* outB     = (const float*)d_in[10];
  const float* lng      = (const float*)d_in[11];
  const float* lnb      = (const float*)d_in[12];
  const float* sw1      = (const float*)d_in[13];
  const float* sb1      = (const float*)d_in[14];
  const float* sw2      = (const float*)d_in[15];
  const float* sb2      = (const float*)d_in[16];
  const float* fw1      = (const float*)d_in[17];
  const float* fb1      = (const float*)d_in[18];
  const float* fw2      = (const float*)d_in[19];
  const float* fb2      = (const float*)d_in[20];
  const float* segw1    = (const float*)d_in[21];
  const float* segb1    = (const float*)d_in[22];
  const float* segw2    = (const float*)d_in[23];
  const float* segb2    = (const float*)d_in[24];
  char* ws = (char*)d_ws;
  float* out0 = (float*)d_out;
  float* out_seg = out0 + 65536;                 // (N,3,HW)
  float* out_probs = out_seg + 12582912;         // (S,N,3)
  float* part = out_seg;                         // scratch overlay, zeroed before seg

  // allow 128 KB dynamic LDS for sort_kernel (gfx950 LDS/CU = 160 KB; grid = 1 block/CU)
  static bool s_attr_done = false;
  if (!s_attr_done){
    (void)hipFuncSetAttribute(reinterpret_cast<const void*>(sort_kernel),
                              hipFuncAttributeMaxDynamicSharedMemorySize, 131072);
    s_attr_done = true;
  }

  prep0_kernel<<<1216, 256, 0, stream>>>(inW, outW, sw1, sw2, segw1, fw1, ws);
  prep1_kernel<<<256, 128, 0, stream>>>(segw1, fw2, fb2, ws);
  qk_kernel<<<256, 256, 0, stream>>>(slots, inW, inB, ws);
  sort_kernel<<<256, 1024, 131072, stream>>>(curio, cov_sel, ws);
  attn_part_kernel<<<2048, 256, 0, stream>>>(features, pos, batch, ws, part);
  attn_reduce_kernel<<<256, 256, 0, stream>>>(slots, inB, outB, lng, lnb, sb1, sb2, segb1,
                                              ws, part, out0);
  zero_kernel<<<2048, 256, 0, stream>>>((float4*)out_seg);
  seg_kernel<<<2048, 256, 0, stream>>>(fb1, segw2, segb2, ws, out_seg, out_probs);
}

// Round 4
// 513.765 us; speedup vs baseline: 1.1258x; 1.0068x over previous
//
#include <hip/hip_runtime.h>
#include <hip/hip_bf16.h>

// Problem constants
#define D_   256
#define HW_  16384
#define B_   8
#define N_   256
#define S_   256
#define NH_  8
#define DH_  32
#define IMP_ 192
#define COV_ 64

// ---------------- workspace layout (byte offsets) ----------------
#define WS_SEL      ((size_t)0)                      // int32 [N][S]  (bit31 = scatter-suppress)
#define WS_KEYSB    ((size_t)262144)                 // bf16  [S][N][D]
#define WS_QK       ((size_t)33816576)               // f32   [N][8][256]
#define WS_QB       ((size_t)35913728)               // f32   [N][8]
#define WS_C1       ((size_t)35921920)               // f32   [N][256]
#define WS_WQT      ((size_t)36184064)               // f32   [256][256]  wqT[e][i]
#define WS_WVT      ((size_t)36446208)               // f32   [256][256]  wvT[d][i]
#define WS_WOUTT    ((size_t)36708352)               // f32   [256][256]  WoutT[j][i]
#define WS_SW1T     ((size_t)36970496)               // f32   [256][128]
#define WS_SW2T     ((size_t)37101568)               // f32   [128][128]
#define WS_W1AT     ((size_t)37167104)               // f32   [128][256]
#define WS_FW1B     ((size_t)37298176)               // bf16  [128][256]
#define WS_WFUSE    ((size_t)37363712)               // bf16  [256][128]  Wfuse[i][e] = seg_w1b . fw2
#define WS_ADDC     ((size_t)37429248)               // f32   [256]       addc[i] = seg_w1b . fb2

// attention partials live in d_out's out_seg region (zeroed AFTER attn_reduce)
#define PR_R_OFF  ((size_t)0)         // f32 [n][tile][h][256]  (4194304 floats)
#define PR_M_OFF  ((size_t)4194304)   // f32 [n][tile][h]
#define PR_L_OFF  ((size_t)4210688)   // f32 [n][tile][h]

typedef short bf16x8 __attribute__((ext_vector_type(8)));
typedef float f32x4  __attribute__((ext_vector_type(4)));

__device__ __forceinline__ unsigned short f2bf(float x){
  unsigned u = __float_as_uint(x);
  u = u + 0x7FFFu + ((u >> 16) & 1u);   // round-to-nearest-even
  return (unsigned short)(u >> 16);
}
__device__ __forceinline__ float bf2f(unsigned short h){
  return __uint_as_float(((unsigned)h) << 16);
}
// bijective LDS swizzle: toggles bank bits [5:1] with bits [10:6] -> pass-start
// reads (16 consecutive u16 per lane) become 2-way (free); scatter stays random.
__device__ __forceinline__ unsigned swz(unsigned p){ return p ^ (((p >> 6) & 31u) << 1); }

// ---------------- prep0: weight transposes / bf16 casts ----------------
__global__ __launch_bounds__(256) void prep0_kernel(
    const float* __restrict__ inW, const float* __restrict__ outW,
    const float* __restrict__ sw1, const float* __restrict__ sw2,
    const float* __restrict__ segw1, const float* __restrict__ fw1,
    char* __restrict__ ws)
{
  int idx = blockIdx.x * 256 + threadIdx.x;
  float* wqT   = (float*)(ws + WS_WQT);
  float* wvT   = (float*)(ws + WS_WVT);
  float* WoutT = (float*)(ws + WS_WOUTT);
  float* sw1T  = (float*)(ws + WS_SW1T);
  float* sw2T  = (float*)(ws + WS_SW2T);
  float* W1aT  = (float*)(ws + WS_W1AT);
  unsigned short* fw1b = (unsigned short*)(ws + WS_FW1B);
  if (idx < 65536){                       // wqT[e][i] = Wq[i][e]
    int e = idx >> 8, i = idx & 255; wqT[idx] = inW[i*256 + e];
  } else if (idx < 131072){               // wvT[d][i] = Wv[i][d]
    int r = idx - 65536; int d = r >> 8, i = r & 255; wvT[r] = inW[(512 + i)*256 + d];
  } else if (idx < 196608){               // WoutT[j][i] = Wout[i][j]
    int r = idx - 131072; int j = r >> 8, i = r & 255; WoutT[r] = outW[i*256 + j];
  } else if (idx < 229376){               // sw1T[e][t] = slot_w1[t][e]
    int r = idx - 196608; int e = r >> 7, t = r & 127; sw1T[r] = sw1[t*256 + e];
  } else if (idx < 245760){               // sw2T[e][j] = slot_w2[j][e]
    int r = idx - 229376; int e = r >> 7, j = r & 127; sw2T[r] = sw2[j*128 + e];
  } else if (idx < 278528){               // W1aT[j][i] = seg_w1[i][j], j<128
    int r = idx - 245760; int j = r >> 8, i = r & 255; W1aT[r] = segw1[i*256 + j];
  } else if (idx < 311296){               // fw1 bf16
    int r = idx - 278528; fw1b[r] = f2bf(fw1[r]);
  }
}

// ---------------- prep1: Wfuse = seg_w1[:,128:] @ fw2 ; addc = seg_w1[:,128:] @ fb2 ----------------
__global__ __launch_bounds__(128) void prep1_kernel(
    const float* __restrict__ segw1, const float* __restrict__ fw2,
    const float* __restrict__ fb2, char* __restrict__ ws)
{
  __shared__ float tmp[128];
  int i = blockIdx.x, t = threadIdx.x;   // t = e
  unsigned short* WfuseB = (unsigned short*)(ws + WS_WFUSE);
  float* addc = (float*)(ws + WS_ADDC);
  const float* w1b = segw1 + (size_t)i*256 + 128;
  float acc = 0.f;
  #pragma unroll 16
  for (int k = 0; k < 128; k++) acc += w1b[k] * fw2[k*128 + t];
  WfuseB[i*128 + t] = f2bf(acc);
  tmp[t] = w1b[t] * fb2[t];
  __syncthreads();
  if (t == 0){
    float s = 0.f;
    #pragma unroll 16
    for (int k = 0; k < 128; k++) s += tmp[k];
    addc[i] = s;
  }
}

// ---------------- qk: q = (slots@WqT+bq)/sqrt(DH); qk[n][h][e] = sum_dh q*Wk ----------------
__global__ __launch_bounds__(256) void qk_kernel(
    const float* __restrict__ slots, const float* __restrict__ inW,
    const float* __restrict__ inB, char* __restrict__ ws)
{
  __shared__ float sl[256];
  __shared__ float ql[256];
  int n = blockIdx.x, t = threadIdx.x;
  const float* wqT = (const float*)(ws + WS_WQT);
  float* qk = (float*)(ws + WS_QK);
  float* qb = (float*)(ws + WS_QB);
  sl[t] = slots[n*256 + t];
  __syncthreads();
  float acc = inB[t];
  #pragma unroll 16
  for (int e = 0; e < 256; e++) acc += sl[e] * wqT[e*256 + t];
  ql[t] = acc * 0.17677669529663687f;   // 1/sqrt(32)
  __syncthreads();
  for (int h = 0; h < 8; h++){
    float a = 0.f;
    const float* wrow = inW + (size_t)(256 + h*32) * 256;
    #pragma unroll 16
    for (int dp = 0; dp < 32; dp++) a += ql[h*32 + dp] * wrow[dp*256 + t];
    qk[((size_t)n*8 + h)*256 + t] = a;
  }
  if (t < 8){
    float a = 0.f;
    #pragma unroll 8
    for (int dp = 0; dp < 32; dp++) a += ql[t*32 + dp] * inB[256 + t*32 + dp];
    qb[n*8 + t] = a;
  }
}

// ---------------- sort: per-row stable LSD radix argsort (descending) + suppress bit ----------------
// Keys computed once (coalesced) into a 64 KB LDS keybuf; all 8 passes' digit fetches are
// random ds_read_b32 instead of random global gathers. 128 KB dynamic LDS, 1 block/CU.
__global__ __launch_bounds__(1024) void sort_kernel(
    const float* __restrict__ curio, const int* __restrict__ cov_sel,
    char* __restrict__ ws)
{
  extern __shared__ char smem_dyn[];
  unsigned*       keybuf = (unsigned*)smem_dyn;                   // 64 KB, by element id
  unsigned short* idxbuf = (unsigned short*)(smem_dyn + 65536);   // 32 KB (swizzled layout)
  unsigned short* hist   = (unsigned short*)(smem_dyn + 98304);   // 32 KB: slot = d*1024 + tid
  int n = blockIdx.x, tid = threadIdx.x;
  int lane = tid & 63, wid = tid >> 6;       // 16 waves
  const float* row = curio + (size_t)n * 16384;
  int* sel = (int*)(ws + WS_SEL);
  // one-time key transform, fully coalesced (4 x float4 per thread)
  {
    const float4* rowv = (const float4*)row;
    #pragma unroll
    for (int i = 0; i < 4; i++){
      float4 v = rowv[tid + i*1024];
      float vv[4] = {v.x, v.y, v.z, v.w};
      unsigned k4[4];
      #pragma unroll
      for (int c = 0; c < 4; c++){
        unsigned u = __float_as_uint(vv[c]);
        k4[c] = ((int)u < 0) ? u : (~u & 0x7fffffffu);  // ascending = value desc
      }
      uint4 w; w.x = k4[0]; w.y = k4[1]; w.z = k4[2]; w.w = k4[3];
      ((uint4*)keybuf)[tid + i*1024] = w;
    }
  }
  unsigned myidx[16]; unsigned myd[16];
  for (int pass = 0; pass < 8; pass++){
    unsigned* h32 = (unsigned*)hist;
    #pragma unroll
    for (int i = 0; i < 8; i++) h32[tid + i*1024] = 0;
    int base = tid * 16;
    if (pass == 0){
      #pragma unroll
      for (int i = 0; i < 16; i++) myidx[i] = base + i;
    } else {
      #pragma unroll
      for (int i = 0; i < 16; i++) myidx[i] = idxbuf[swz(base + i)];
    }
    __syncthreads();   // hist zeroed; keybuf (pass 0) / idxbuf reads complete
    int shift = pass * 4;
    #pragma unroll
    for (int i = 0; i < 16; i++){
      unsigned key = keybuf[myidx[i]];
      unsigned d = (key >> shift) & 15u;
      myd[i] = d;
      hist[d*1024 + tid]++;
    }
    __syncthreads();
    // exclusive scan over linear (digit-major, thread-minor) hist: 16384 entries, 16/thread
    unsigned v16[16]; unsigned srun = 0;
    #pragma unroll
    for (int j = 0; j < 16; j++) v16[j] = hist[tid*16 + j];
    #pragma unroll
    for (int j = 0; j < 16; j++){ unsigned tv = v16[j]; v16[j] = srun; srun += tv; }
    unsigned inc = srun;
    for (int dlt = 1; dlt < 64; dlt <<= 1){
      unsigned o = (unsigned)__shfl_up((int)inc, dlt, 64);
      if (lane >= dlt) inc += o;
    }
    unsigned* wtt = (unsigned*)idxbuf;   // scratch: idxbuf content is dead here (myidx in regs)
    if (lane == 63) wtt[wid] = inc;
    __syncthreads();
    if (tid == 0){ unsigned r = 0; for (int w = 0; w < 16; w++){ unsigned x = wtt[w]; wtt[w] = r; r += x; } }
    __syncthreads();
    unsigned off = wtt[wid] + (inc - srun);
    #pragma unroll
    for (int j = 0; j < 16; j++) hist[tid*16 + j] = (unsigned short)(v16[j] + off);
    __syncthreads();
    #pragma unroll
    for (int i = 0; i < 16; i++){
      unsigned d = myd[i];
      unsigned short pos = hist[d*1024 + tid];
      hist[d*1024 + tid] = (unsigned short)(pos + 1);
      idxbuf[swz(pos)] = (unsigned short)myidx[i];
    }
    __syncthreads();
  }
  // sel with suppress bit (numpy fancy-assign: largest s wins on duplicate j)
  int* sel_l = (int*)hist;   // hist dead after final scatter
  if (tid < 256){
    int s = tid;
    int rank = (s < IMP_) ? s : (IMP_ + cov_sel[s - IMP_]);
    sel_l[s] = (int)idxbuf[swz(rank)];
  }
  __syncthreads();
  if (tid < 256){
    int s = tid;
    int v = sel_l[s];
    if (s >= IMP_){
      for (int s2 = s + 1; s2 < 256; s2++)
        if (sel_l[s2] == v){ v |= 0x80000000; break; }
    }
    sel[n*256 + s] = v;
  }
}

// ---------------- attn_part: per (n, s-tile) gather + partial softmax stats; emits bf16 keys ----------------
// v4: keys_l LDS buffer DELETED -- each thread computes partial logits for all 8 heads from
// its in-register f32 key chunk (kk[32]) and reduces across the 8 chunk-lanes via shfl_xor.
// qk_l re-laid as [h][chunk(8)][36] f32: 36*4B=144 (16B-aligned rows) and 36*chunk mod 32 =
// 4*chunk spreads the 8 chunks across banks with compile-time register indices.
// LDS 43.5KB -> 27.3KB => 3 -> 5 blocks/CU (occupancy was the binding constraint).
__global__ __launch_bounds__(256) void attn_part_kernel(
    const float* __restrict__ features, const float* __restrict__ pos,
    const int* __restrict__ batch_idx, char* __restrict__ ws,
    float* __restrict__ part)
{
  __shared__ __align__(16) float qk_l[8*288];              // [h][chunk][36]
  __shared__ float qb_l[8];
  __shared__ __align__(16) unsigned short f_l[32*264];
  __shared__ float lg[32*9];
  int bx = blockIdx.x;
  int n = bx >> 3, tile = bx & 7;
  int t = threadIdx.x;
  const int* sel = (const int*)(ws + WS_SEL);
  unsigned short* keysb = (unsigned short*)(ws + WS_KEYSB);
  const float* qk  = (const float*)(ws + WS_QK);
  const float* qb  = (const float*)(ws + WS_QB);
  int b = batch_idx[n];
  #pragma unroll
  for (int r = 0; r < 8; r++){   // stage qk: [h=r][chunk=t>>5][j=t&31]
    qk_l[r*288 + (t>>5)*36 + (t&31)] = qk[((size_t)n*8 + r)*256 + t];
  }
  if (t < 8) qb_l[t] = qb[n*8 + t];
  int srow = t >> 3, chunk = t & 7;
  int s = tile*32 + srow;
  int hw = sel[n*256 + s] & 0x7fffffff;
  size_t gb = ((size_t)hw * 8 + (size_t)b) * 256 + (size_t)chunk*32;
  const float4* fp = (const float4*)(features + gb);
  const float4* pp = (const float4*)(pos + gb);
  float ff[32], kk[32];
  #pragma unroll
  for (int q = 0; q < 8; q++){
    float4 a = fp[q]; float4 c = pp[q];
    ff[q*4+0]=a.x; ff[q*4+1]=a.y; ff[q*4+2]=a.z; ff[q*4+3]=a.w;
    kk[q*4+0]=a.x+c.x; kk[q*4+1]=a.y+c.y; kk[q*4+2]=a.z+c.z; kk[q*4+3]=a.w+c.w;
  }
  unsigned kw[16], fw[16];
  #pragma unroll
  for (int p = 0; p < 16; p++){
    kw[p] = (unsigned)f2bf(kk[2*p]) | ((unsigned)f2bf(kk[2*p+1]) << 16);
    fw[p] = (unsigned)f2bf(ff[2*p]) | ((unsigned)f2bf(ff[2*p+1]) << 16);
  }
  { // f_l write: 4 x ds_write_b128 (row stride 264 u16 = 528 B, 16B-aligned)
    uint4* frow = (uint4*)&f_l[srow*264 + chunk*32];
    #pragma unroll
    for (int q = 0; q < 4; q++){
      uint4 u; u.x = fw[4*q]; u.y = fw[4*q+1]; u.z = fw[4*q+2]; u.w = fw[4*q+3];
      frow[q] = u;
    }
  }
  uint4* gk = (uint4*)(keysb + ((size_t)s*256 + n)*256 + chunk*32);
  #pragma unroll
  for (int q = 0; q < 4; q++){
    uint4 u; u.x = kw[4*q]; u.y = kw[4*q+1]; u.z = kw[4*q+2]; u.w = kw[4*q+3];
    gk[q] = u;
  }
  __syncthreads();
  { // logits: thread (srow,chunk) -> partials for all 8 h over its own f32 kk[32]
    float pl[8];
    #pragma unroll
    for (int h = 0; h < 8; h++){
      const float4* qh = (const float4*)&qk_l[h*288 + chunk*36];
      float acc = 0.f;
      #pragma unroll
      for (int j4 = 0; j4 < 8; j4++){
        float4 qa = qh[j4];
        acc += kk[j4*4+0]*qa.x + kk[j4*4+1]*qa.y
             + kk[j4*4+2]*qa.z + kk[j4*4+3]*qa.w;
      }
      pl[h] = acc;
    }
    // reduce over the 8 chunk-lanes (consecutive lanes within the wave)
    #pragma unroll
    for (int off = 1; off < 8; off <<= 1){
      #pragma unroll
      for (int h = 0; h < 8; h++) pl[h] += __shfl_xor(pl[h], off, 64);
    }
    lg[srow*9 + chunk] = pl[chunk] + qb_l[chunk];   // thread's chunk == written h
  }
  __syncthreads();
  if (t < 8){ // per-tile softmax partial (no running state)
    float mt = -1e30f;
    for (int s2 = 0; s2 < 32; s2++) mt = fmaxf(mt, lg[s2*9 + t]);
    float ls = 0.f;
    for (int s2 = 0; s2 < 32; s2++){ float w = __expf(lg[s2*9 + t] - mt); lg[s2*9 + t] = w; ls += w; }
    part[PR_M_OFF + (size_t)(n*8 + tile)*8 + t] = mt;
    part[PR_L_OFF + (size_t)(n*8 + tile)*8 + t] = ls;
  }
  __syncthreads();
  { // r[h][d] partial (values = f); thread owns d = dg*8 .. dg*8+7 (one b128 per s-step)
    int h_r = t >> 5, dg = t & 31;
    float racc[8];
    #pragma unroll
    for (int j = 0; j < 8; j++) racc[j] = 0.f;
    for (int s2 = 0; s2 < 32; s2++){
      float w = lg[s2*9 + h_r];
      uint4 u = *(const uint4*)&f_l[s2*264 + dg*8];
      racc[0] += w * bf2f((unsigned short)(u.x & 0xffffu));
      racc[1] += w * bf2f((unsigned short)(u.x >> 16));
      racc[2] += w * bf2f((unsigned short)(u.y & 0xffffu));
      racc[3] += w * bf2f((unsigned short)(u.y >> 16));
      racc[4] += w * bf2f((unsigned short)(u.z & 0xffffu));
      racc[5] += w * bf2f((unsigned short)(u.z >> 16));
      racc[6] += w * bf2f((unsigned short)(u.w & 0xffffu));
      racc[7] += w * bf2f((unsigned short)(u.w >> 16));
    }
    float* pr = part + PR_R_OFF + ((size_t)(n*8 + tile)*8 + h_r)*256 + dg*8;
    float4 o0 = {racc[0], racc[1], racc[2], racc[3]};
    float4 o1 = {racc[4], racc[5], racc[6], racc[7]};
    *(float4*)pr = o0;
    *(float4*)(pr + 4) = o1;
  }
}

// ---------------- attn_reduce: combine partials, Wv/Wout GEMVs, residual+LN -> out0; fused c1 ----------------
__global__ __launch_bounds__(256) void attn_reduce_kernel(
    const float* __restrict__ slots, const float* __restrict__ inB,
    const float* __restrict__ outB, const float* __restrict__ lng,
    const float* __restrict__ lnb, const float* __restrict__ sb1,
    const float* __restrict__ sb2, const float* __restrict__ segb1,
    char* __restrict__ ws, const float* __restrict__ part,
    float* __restrict__ out0)
{
  __shared__ float wt_l[8*8];  // [tile][h]
  __shared__ float r_l[8*257];
  __shared__ float o_l[256];
  __shared__ float red[4];
  __shared__ float so[256];
  __shared__ float h1[128];
  __shared__ float ps[128];
  int n = blockIdx.x, t = threadIdx.x;
  const float* wvT  = (const float*)(ws + WS_WVT);
  const float* WoT  = (const float*)(ws + WS_WOUTT);
  const float* sw1T = (const float*)(ws + WS_SW1T);
  const float* sw2T = (const float*)(ws + WS_SW2T);
  const float* W1aT = (const float*)(ws + WS_W1AT);
  const float* addc2 = (const float*)(ws + WS_ADDC);
  float* c1 = (float*)(ws + WS_C1);
  if (t < 8){
    float m8[8], l8[8];
    #pragma unroll
    for (int t8 = 0; t8 < 8; t8++){
      m8[t8] = part[PR_M_OFF + (size_t)(n*8 + t8)*8 + t];
      l8[t8] = part[PR_L_OFF + (size_t)(n*8 + t8)*8 + t];
    }
    float M = -1e30f;
    #pragma unroll
    for (int t8 = 0; t8 < 8; t8++) M = fmaxf(M, m8[t8]);
    float L = 0.f;
    #pragma unroll
    for (int t8 = 0; t8 < 8; t8++){
      float sc = __expf(m8[t8] - M);
      wt_l[t8*8 + t] = sc;
      L += l8[t8] * sc;
    }
    float inv = 1.f / L;
    #pragma unroll
    for (int t8 = 0; t8 < 8; t8++) wt_l[t8*8 + t] *= inv;
  }
  __syncthreads();
  { // combine partials; thread owns d = dg*8 .. dg*8+7 (matches attn_part layout)
    int h_r = t >> 5, dg = t & 31;
    float rj[8];
    #pragma unroll
    for (int j = 0; j < 8; j++) rj[j] = 0.f;
    #pragma unroll
    for (int t8 = 0; t8 < 8; t8++){
      float w = wt_l[t8*8 + h_r];
      const float* pr = part + PR_R_OFF + ((size_t)(n*8 + t8)*8 + h_r)*256 + dg*8;
      float4 p0 = *(const float4*)pr;
      float4 p1 = *(const float4*)(pr + 4);
      rj[0] += w * p0.x; rj[1] += w * p0.y; rj[2] += w * p0.z; rj[3] += w * p0.w;
      rj[4] += w * p1.x; rj[5] += w * p1.y; rj[6] += w * p1.z; rj[7] += w * p1.w;
    }
    #pragma unroll
    for (int j = 0; j < 8; j++) r_l[h_r*257 + dg*8 + j] = rj[j];
  }
  __syncthreads();
  { // o[i] = sum_e r[h][e]*WvT[e][i] + bv[i]
    float acc = inB[512 + t];
    const float* rh = &r_l[(t >> 5)*257];
    #pragma unroll 16
    for (int d = 0; d < 256; d++) acc += rh[d] * wvT[d*256 + t];
    o_l[t] = acc;
  }
  __syncthreads();
  float x;
  { // delta + residual
    float acc = outB[t];
    #pragma unroll 16
    for (int j = 0; j < 256; j++) acc += o_l[j] * WoT[j*256 + t];
    x = slots[n*256 + t] + acc;
  }
  // layernorm over D
  int lane = t & 63, wid = t >> 6;
  float v = x;
  for (int o = 32; o > 0; o >>= 1) v += __shfl_xor(v, o, 64);
  if (lane == 0) red[wid] = v;
  __syncthreads();
  float mu = (red[0] + red[1] + red[2] + red[3]) * (1.f/256.f);
  float xc = x - mu;
  __syncthreads();
  float v2 = xc * xc;
  for (int o = 32; o > 0; o >>= 1) v2 += __shfl_xor(v2, o, 64);
  if (lane == 0) red[wid] = v2;
  __syncthreads();
  float var = (red[0] + red[1] + red[2] + red[3]) * (1.f/256.f);
  float xo = xc * rsqrtf(var + 1e-5f) * lng[t] + lnb[t];
  out0[n*256 + t] = xo;
  so[t] = xo;
  __syncthreads();
  // ---- fused c1: proj_slots MLP folded into seg layer-1 constant ----
  if (t < 128){
    float a = sb1[t];
    #pragma unroll 16
    for (int e = 0; e < 256; e++) a += so[e] * sw1T[e*128 + t];
    h1[t] = fmaxf(a, 0.f);
  }
  __syncthreads();
  if (t < 128){
    float a = sb2[t];
    #pragma unroll 16
    for (int e = 0; e < 128; e++) a += h1[e] * sw2T[e*128 + t];
    ps[t] = a;
  }
  __syncthreads();
  float a = segb1[t] + addc2[t];
  #pragma unroll 16
  for (int j = 0; j < 128; j++) a += ps[j] * W1aT[j*256 + t];
  c1[n*256 + t] = a;
}

// ---------------- zero: exact 48 MiB streaming clear of out_seg (replaces runtime fill) ----------------
// 12582912 floats = 3145728 float4; 2048 blocks x 256 thr x 6 = 3145728 exactly.
__global__ __launch_bounds__(256) void zero_kernel(float4* __restrict__ p)
{
  int i = blockIdx.x * 256 + threadIdx.x;
  float4 z = {0.f, 0.f, 0.f, 0.f};
  #pragma unroll
  for (int q = 0; q < 6; q++) p[i + q*524288] = z;
}

// ---------------- seg: fused MFMA chain keys->h1->(fused L2+seg L1)->3-way softmax + scatter ----------------
__global__ __launch_bounds__(256) void seg_kernel(
    const float* __restrict__ fb1, const float* __restrict__ segw2,
    const float* __restrict__ segb2, char* __restrict__ ws,
    float* __restrict__ out_seg, float* __restrict__ out_probs)
{
  __shared__ char smem[65024];
  unsigned short* A0   = (unsigned short*)smem;                       // [32][264]
  unsigned short* Bs   = (unsigned short*)(smem + 16896);             // [128][136]
  unsigned short* A1   = (unsigned short*)(smem + 16896 + 34816);     // [32][136]
  float* sw2_l = (float*)(smem + 16896 + 34816 + 8704);               // [3][256]
  float* lg3p  = (float*)(smem + 16896 + 34816 + 8704 + 3072);        // [4][32][3]
  int t = threadIdx.x;
  int wave = t >> 6, lane = t & 63, quad = lane >> 4, l15 = lane & 15;
  int rho0 = blockIdx.x * 32;
  int sg = rho0 >> 8, n0 = rho0 & 255;
  const unsigned short* keysb  = (const unsigned short*)(ws + WS_KEYSB);
  const unsigned short* fw1b   = (const unsigned short*)(ws + WS_FW1B);
  const unsigned short* WfuseB = (const unsigned short*)(ws + WS_WFUSE);
  const float* c1 = (const float*)(ws + WS_C1);
  const int* sel  = (const int*)(ws + WS_SEL);
  f32x4 zf = {0.f, 0.f, 0.f, 0.f};

  for (int i = t; i < 768; i += 256) sw2_l[i] = segw2[i];
  { // stage A0 = keys tile (32 rows x 256 bf16)
    int r = t >> 3, c8 = t & 7;
    const uint4* src = (const uint4*)(keysb + ((size_t)(rho0 + r))*256 + c8*32);
    uint4* dst = (uint4*)(A0 + r*264 + c8*32);
    #pragma unroll
    for (int q = 0; q < 4; q++) dst[q] = src[q];
  }
  // ---- GEMM1: [32x256]x[256->128] ----
  f32x4 acc[2][2];
  #pragma unroll
  for (int mt = 0; mt < 2; mt++)
    #pragma unroll
    for (int nt = 0; nt < 2; nt++) acc[mt][nt] = zf;
  for (int kh = 0; kh < 2; kh++){
    __syncthreads();
    { int r = t >> 1, h2 = t & 1;
      const uint4* src = (const uint4*)(fw1b + r*256 + kh*128 + h2*64);
      uint4* dst = (uint4*)(Bs + r*136 + h2*64);
      #pragma unroll
      for (int q = 0; q < 8; q++) dst[q] = src[q];
    }
    __syncthreads();
    #pragma unroll
    for (int ks = 0; ks < 4; ks++){
      int k = ks * 32;
      bf16x8 a[2], bb[2];
      #pragma unroll
      for (int mt = 0; mt < 2; mt++) a[mt]  = *(const bf16x8*)(A0 + (mt*16 + l15)*264 + kh*128 + k + quad*8);
      #pragma unroll
      for (int nt = 0; nt < 2; nt++) bb[nt] = *(const bf16x8*)(Bs + (wave*32 + nt*16 + l15)*136 + k + quad*8);
      #pragma unroll
      for (int mt = 0; mt < 2; mt++)
        #pragma unroll
        for (int nt = 0; nt < 2; nt++)
          acc[mt][nt] = __builtin_amdgcn_mfma_f32_16x16x32_bf16(a[mt], bb[nt], acc[mt][nt], 0, 0, 0);
    }
  }
  #pragma unroll
  for (int mt = 0; mt < 2; mt++)
    #pragma unroll
    for (int nt = 0; nt < 2; nt++){
      int col = wave*32 + nt*16 + l15;
      float bias = fb1[col];
      #pragma unroll
      for (int r = 0; r < 4; r++){
        int m = mt*16 + quad*4 + r;
        A1[m*136 + col] = f2bf(fmaxf(acc[mt][nt][r] + bias, 0.f));
      }
    }
  // ---- GEMMf: [32x128 (h1)] x [128->256 Wfuse], fused +c1, relu, x seg_w2 (N=3) ----
  float pl[2][4][3];
  #pragma unroll
  for (int mt = 0; mt < 2; mt++)
    #pragma unroll
    for (int r = 0; r < 4; r++)
      #pragma unroll
      for (int c = 0; c < 3; c++) pl[mt][r][c] = 0.f;
  for (int nh = 0; nh < 2; nh++){
    __syncthreads();
    { int r = t >> 1, h2 = t & 1;
      const uint4* src = (const uint4*)(WfuseB + (size_t)(nh*128 + r)*128 + h2*64);
      uint4* dst = (uint4*)(Bs + r*136 + h2*64);
      #pragma unroll
      for (int q = 0; q < 8; q++) dst[q] = src[q];
    }
    __syncthreads();
    f32x4 acc3[2][2];
    #pragma unroll
    for (int mt = 0; mt < 2; mt++)
      #pragma unroll
      for (int nt = 0; nt < 2; nt++) acc3[mt][nt] = zf;
    #pragma unroll
    for (int ks = 0; ks < 4; ks++){
      int k = ks * 32;
      bf16x8 a[2], bb[2];
      #pragma unroll
      for (int mt = 0; mt < 2; mt++) a[mt]  = *(const bf16x8*)(A1 + (mt*16 + l15)*136 + k + quad*8);
      #pragma unroll
      for (int nt = 0; nt < 2; nt++) bb[nt] = *(const bf16x8*)(Bs + (wave*32 + nt*16 + l15)*136 + k + quad*8);
      #pragma unroll
      for (int mt = 0; mt < 2; mt++)
        #pragma unroll
        for (int nt = 0; nt < 2; nt++)
          acc3[mt][nt] = __builtin_amdgcn_mfma_f32_16x16x32_bf16(a[mt], bb[nt], acc3[mt][nt], 0, 0, 0);
    }
    #pragma unroll
    for (int mt = 0; mt < 2; mt++)
      #pragma unroll
      for (int nt = 0; nt < 2; nt++){
        int i = nh*128 + wave*32 + nt*16 + l15;
        #pragma unroll
        for (int r = 0; r < 4; r++){
          int m = mt*16 + quad*4 + r;
          float hv = acc3[mt][nt][r] + c1[(size_t)(n0 + m)*256 + i];
          hv = fmaxf(hv, 0.f);
          #pragma unroll
          for (int c = 0; c < 3; c++) pl[mt][r][c] += hv * sw2_l[c*256 + i];
        }
      }
  }
  // reduce partial logits over the 16 lanes holding different i-columns
  #pragma unroll
  for (int off = 1; off < 16; off <<= 1){
    #pragma unroll
    for (int mt = 0; mt < 2; mt++)
      #pragma unroll
      for (int r = 0; r < 4; r++)
        #pragma unroll
        for (int c = 0; c < 3; c++)
          pl[mt][r][c] += __shfl_xor(pl[mt][r][c], off, 64);
  }
  if (l15 == 0){
    #pragma unroll
    for (int mt = 0; mt < 2; mt++)
      #pragma unroll
      for (int r = 0; r < 4; r++){
        int m = mt*16 + quad*4 + r;
        #pragma unroll
        for (int c = 0; c < 3; c++) lg3p[(wave*32 + m)*3 + c] = pl[mt][r][c];
      }
  }
  __syncthreads();
  if (t < 32){
    int m = t; int n = n0 + m;
    float L[3];
    #pragma unroll
    for (int c = 0; c < 3; c++)
      L[c] = segb2[c] + lg3p[(0*32 + m)*3 + c] + lg3p[(1*32 + m)*3 + c]
                      + lg3p[(2*32 + m)*3 + c] + lg3p[(3*32 + m)*3 + c];
    float mx = fmaxf(L[0], fmaxf(L[1], L[2]));
    float e0 = __expf(L[0] - mx), e1 = __expf(L[1] - mx), e2 = __expf(L[2] - mx);
    float inv = 1.f / (e0 + e1 + e2);
    float p0 = e0*inv, p1 = e1*inv, p2 = e2*inv;
    size_t rho = (size_t)rho0 + m;
    out_probs[rho*3 + 0] = p0; out_probs[rho*3 + 1] = p1; out_probs[rho*3 + 2] = p2;
    int v = sel[n*256 + sg];
    if (!(v & 0x80000000)){
      int j = v & 0x7fffffff;
      out_seg[((size_t)n*3 + 0)*16384 + j] = p0;
      out_seg[((size_t)n*3 + 1)*16384 + j] = p1;
      out_seg[((size_t)n*3 + 2)*16384 + j] = p2;
    }
  }
}

// ---------------- launch ----------------
extern "C" void kernel_launch(void* const* d_in, const int* in_sizes, int n_in,
                              void* d_out, int out_size, void* d_ws, size_t ws_size,
                              hipStream_t stream)
{
  (void)in_sizes; (void)n_in; (void)out_size; (void)ws_size;
  const float* features = (const float*)d_in[0];
  const float* pos      = (const float*)d_in[1];
  const int*   batch    = (const int*)d_in[2];
  const float* curio    = (const float*)d_in[3];
  const float* slots    = (const float*)d_in[5];
  const int*   cov_sel  = (const int*)d_in[6];
  const float* inW      = (const float*)d_in[7];
  const float* inB      = (const float*)d_in[8];
  const float* outW     = (const float*)d_in[9];
  const float* outB     = (const float*)d_in[10];
  const float* lng      = (const float*)d_in[11];
  const float* lnb      = (const float*)d_in[12];
  const float* sw1      = (const float*)d_in[13];
  const float* sb1      = (const float*)d_in[14];
  const float* sw2      = (const float*)d_in[15];
  const float* sb2      = (const float*)d_in[16];
  const float* fw1      = (const float*)d_in[17];
  const float* fb1      = (const float*)d_in[18];
  const float* fw2      = (const float*)d_in[19];
  const float* fb2      = (const float*)d_in[20];
  const float* segw1    = (const float*)d_in[21];
  const float* segb1    = (const float*)d_in[22];
  const float* segw2    = (const float*)d_in[23];
  const float* segb2    = (const float*)d_in[24];
  char* ws = (char*)d_ws;
  float* out0 = (float*)d_out;
  float* out_seg = out0 + 65536;                 // (N,3,HW)
  float* out_probs = out_seg + 12582912;         // (S,N,3)
  float* part = out_seg;                         // scratch overlay, zeroed before seg

  // allow 128 KB dynamic LDS for sort_kernel (gfx950 LDS/CU = 160 KB; grid = 1 block/CU)
  static bool s_attr_done = false;
  if (!s_attr_done){
    (void)hipFuncSetAttribute(reinterpret_cast<const void*>(sort_kernel),
                              hipFuncAttributeMaxDynamicSharedMemorySize, 131072);
    s_attr_done = true;
  }

  prep0_kernel<<<1216, 256, 0, stream>>>(inW, outW, sw1, sw2, segw1, fw1, ws);
  prep1_kernel<<<256, 128, 0, stream>>>(segw1, fw2, fb2, ws);
  qk_kernel<<<256, 256, 0, stream>>>(slots, inW, inB, ws);
  sort_kernel<<<256, 1024, 131072, stream>>>(curio, cov_sel, ws);
  attn_part_kernel<<<2048, 256, 0, stream>>>(features, pos, batch, ws, part);
  attn_reduce_kernel<<<256, 256, 0, stream>>>(slots, inB, outB, lng, lnb, sb1, sb2, segb1,
                                              ws, part, out0);
  zero_kernel<<<2048, 256, 0, stream>>>((float4*)out_seg);
  seg_kernel<<<2048, 256, 0, stream>>>(fb1, segw2, segb2, ws, out_seg, out_probs);
}